// Round 8
// baseline (861.507 us; speedup 1.0000x reference)
//
#include <hip/hip_runtime.h>
#include <hip/hip_fp16.h>

// CLAGCN forward on MI355X.
// R1-R11: counting-sort CSR build, MFMA middle GEMMs. R12: swizzles. R13:
//     LDS-free l1 MFMA + 16-lane dualagg. 669us.
// R14: (a) dualagg column-split (blockIdx.z halves, 8-lane groups): per-XCD
//     gather working set 12.8->6.4MB (vs 4MB L2) -> higher hit rate, less
//     L2-miss traffic. (b) dispatch 26->20: prep fusion (prepW+prepW1+zeroing,
//     kills memset), blocksum folded into scanB, stats2+gate_prep fused via
//     atomic-ticket last-block (stats re-read via atomicAdd(p,0) — coherent
//     since stats were WRITTEN by atomics; preA/B cross kernel boundary).

#define DFEAT 128

typedef __attribute__((ext_vector_type(8))) short bf16x8;
typedef __attribute__((ext_vector_type(4))) float f32x4;

__device__ __forceinline__ unsigned short f2bf(float f) {
    unsigned u = __float_as_uint(f);
    u += 0x7fffu + ((u >> 16) & 1u);
    return (unsigned short)(u >> 16);
}
__device__ __forceinline__ float bf2f(unsigned short u) {
    return __uint_as_float((unsigned)u << 16);
}
__device__ __forceinline__ unsigned f2h16(float f) {
    return (unsigned)__half_as_ushort(__float2half(f));
}
__device__ __forceinline__ float h16f(unsigned u) {
    return __half2float(__ushort_as_half((unsigned short)u));
}
__device__ __forceinline__ float4 bf4tof4(ushort4 u) {
    return make_float4(__uint_as_float((unsigned)u.x << 16),
                       __uint_as_float((unsigned)u.y << 16),
                       __uint_as_float((unsigned)u.z << 16),
                       __uint_as_float((unsigned)u.w << 16));
}
// accumulate 8 bf16 (packed in int4) * w into acc[8]
__device__ __forceinline__ void acc8(float* acc, float w, int4 r) {
    int vs[4] = {r.x, r.y, r.z, r.w};
#pragma unroll
    for (int q = 0; q < 4; ++q) {
        float lo = __uint_as_float((unsigned)vs[q] << 16);
        float hi = __uint_as_float((unsigned)vs[q] & 0xffff0000u);
        acc[q * 2] = fmaf(w, lo, acc[q * 2]);
        acc[q * 2 + 1] = fmaf(w, hi, acc[q * 2 + 1]);
    }
}

// ---------------- two-level counting-sort CSR build ----------------
constexpr int RSH = 13;        // range shift -> 8192 nodes per range
constexpr int RSZ = 8192;
constexpr int NRMAX = 8;       // max ranges (N <= 65536)
constexpr int EPA = 2048;      // edges per partition block
constexpr int SUBS = 16;       // sub-slices per range for hist/fill
constexpr int SCAP = 160000;   // stream capacity per (graph, range)

__global__ __launch_bounds__(256) void partA_kernel(
    const int* __restrict__ src1, const int* __restrict__ dst1,
    const int* __restrict__ src2, const int* __restrict__ dst2,
    int* __restrict__ stg, int* __restrict__ gcount, int E, int nr) {
    int g = blockIdx.y;
    const int* src = g ? src2 : src1;
    const int* dst = g ? dst2 : dst1;
    __shared__ int buf[EPA];
    __shared__ int buf2[EPA];
    __shared__ int cnt8[NRMAX + 1], pre8[NRMAX + 1], base8[NRMAX];
    int t = threadIdx.x;
    if (t < NRMAX) cnt8[t] = 0;
    __syncthreads();
    int e0 = blockIdx.x * EPA;
    int e1 = min(e0 + EPA, E);
    int ec = e1 - e0;
    for (int i = e0 + t; i < e1; i += 256) {
        int d = dst[i];
        int s = src[i];
        buf[i - e0] = (d << 16) | s;
        atomicAdd(&cnt8[d >> RSH], 1);
    }
    __syncthreads();
    if (t == 0) {
        int run = 0;
        for (int r = 0; r < nr; ++r) { pre8[r] = run; run += cnt8[r]; }
        pre8[nr] = run;
    }
    __syncthreads();
    if (t < nr) {
        base8[t] = atomicAdd(&gcount[g * NRMAX + t], cnt8[t]);
        cnt8[t] = 0;
    }
    __syncthreads();
    for (int j = t; j < ec; j += 256) {
        int v = buf[j];
        int d = (unsigned)v >> 16;
        int r = d >> RSH;
        int p = pre8[r] + atomicAdd(&cnt8[r], 1);
        buf2[p] = ((d & (RSZ - 1)) << 16) | (v & 0xFFFF);
    }
    __syncthreads();
    for (int j = t; j < ec; j += 256) {
        int r = 0;
        while (j >= pre8[r + 1]) ++r;
        int gpos = base8[r] + (j - pre8[r]);
        if (gpos < SCAP) stg[((size_t)g * NRMAX + r) * SCAP + gpos] = buf2[j];
    }
}

__global__ __launch_bounds__(256) void histB_kernel(
    const int* __restrict__ stg, const int* __restrict__ gcount,
    int* __restrict__ baseB, int nr) {
    int g = blockIdx.y;
    int r = blockIdx.x / SUBS;
    int sub = blockIdx.x % SUBS;
    __shared__ int hist[RSZ];
    int t = threadIdx.x;
    for (int i = t; i < RSZ; i += 256) hist[i] = 0;
    __syncthreads();
    int len = min(gcount[g * NRMAX + r], SCAP);
    int seg = (len + SUBS - 1) / SUBS;
    int e0 = sub * seg, e1 = min(e0 + seg, len);
    const int* sp = stg + ((size_t)g * NRMAX + r) * SCAP;
    for (int i = e0 + t; i < e1; i += 256) atomicAdd(&hist[(unsigned)sp[i] >> 16], 1);
    __syncthreads();
    int* bp = baseB + (((size_t)(g * NRMAX + r) * SUBS + sub) << RSH);
    for (int i = t; i < RSZ; i += 256) bp[i] = hist[i];
}

// scanB: per-node exclusive prefix over subs -> cnt, PLUS block total -> bsums
__global__ __launch_bounds__(256) void scanB_kernel(
    int* __restrict__ baseB, int* __restrict__ cnt1, int* __restrict__ cnt2,
    int* __restrict__ bsums, int n, int nb) {
    int node = blockIdx.x * 256 + threadIdx.x;
    int g = blockIdx.y;
    int t = threadIdx.x;
    int run = 0;
    if (node < n) {
        int r = node >> RSH, dloc = node & (RSZ - 1);
        int* p = baseB + (((size_t)(g * NRMAX + r) * SUBS) << RSH) + dloc;
#pragma unroll
        for (int s = 0; s < SUBS; ++s) {
            int v = p[(size_t)s << RSH];
            p[(size_t)s << RSH] = run;
            run += v;
        }
        (g ? cnt2 : cnt1)[node] = run;
    }
    __shared__ int red[256];
    red[t] = run;
    __syncthreads();
    for (int o = 128; o > 0; o >>= 1) {
        if (t < o) red[t] += red[t + o];
        __syncthreads();
    }
    if (t == 0) bsums[(size_t)g * nb + blockIdx.x] = red[0];
}

__global__ void scansums_kernel(int* __restrict__ bs, int nb, int* __restrict__ rp1,
                                int* __restrict__ rp2, int n, int E, float* __restrict__ stats) {
    int t = threadIdx.x;  // 64 threads
    if (t < 2) {
        int* b = bs + (size_t)t * nb;
        int run = 0;
        for (int i = 0; i < nb; ++i) {
            int v = b[i];
            b[i] = run;
            run += v;
        }
        (t ? rp2 : rp1)[n] = E;
    }
    for (int i = t; i < 512; i += 64) stats[i] = 0.f;
}

// writerp: 256 nodes/block (matches scanB blocking), in-block scan
__global__ __launch_bounds__(256) void writerp_kernel(
    const int* __restrict__ c1, const int* __restrict__ c2, const int* __restrict__ bs,
    int* __restrict__ rp1, int* __restrict__ rp2,
    float* __restrict__ dv1, float* __restrict__ dv2, int n, int nb) {
    const int* c = blockIdx.y ? c2 : c1;
    int* rp = blockIdx.y ? rp2 : rp1;
    float* dv = blockIdx.y ? dv2 : dv1;
    int t = threadIdx.x;
    int node = blockIdx.x * 256 + t;
    int v = (node < n) ? c[node] : 0;
    __shared__ int red[256];
    red[t] = v;
    __syncthreads();
    for (int o = 1; o < 256; o <<= 1) {
        int x = (t >= o) ? red[t - o] : 0;
        __syncthreads();
        red[t] += x;
        __syncthreads();
    }
    if (node < n) {
        int run = bs[(size_t)blockIdx.y * nb + blockIdx.x] + red[t] - v;
        rp[node] = run;
        dv[node] = rsqrtf((float)(v + 1));  // +1 self-loop
    }
}

__global__ __launch_bounds__(256) void fillC_kernel(
    const int* __restrict__ stg, const int* __restrict__ gcount,
    const int* __restrict__ baseB,
    const int* __restrict__ rp1, const int* __restrict__ rp2,
    const float* __restrict__ dv1, const float* __restrict__ dv2,
    int* __restrict__ cs1, int* __restrict__ cs2, int n, int nr) {
    int g = blockIdx.y;
    int r = blockIdx.x / SUBS;
    int sub = blockIdx.x % SUBS;
    const int* rp = g ? rp2 : rp1;
    const float* dv = g ? dv2 : dv1;
    int* cs = g ? cs2 : cs1;
    __shared__ int off[RSZ];
    int t = threadIdx.x;
    int r0 = r << RSH;
    int rn = min(RSZ, n - r0);
    if (rn <= 0) return;
    const int* bp = baseB + (((size_t)(g * NRMAX + r) * SUBS + sub) << RSH);
    for (int i = t; i < rn; i += 256) off[i] = bp[i] + rp[r0 + i];
    __syncthreads();
    int len = min(gcount[g * NRMAX + r], SCAP);
    int seg = (len + SUBS - 1) / SUBS;
    int e0 = sub * seg, e1 = min(e0 + seg, len);
    const int* sp = stg + ((size_t)g * NRMAX + r) * SCAP;
    for (int i = e0 + t; i < e1; i += 256) {
        int v = sp[i];
        int dloc = (unsigned)v >> 16;
        int s = v & 0xFFFF;
        float w = dv[r0 + dloc] * dv[s];
        int pos = atomicAdd(&off[dloc], 1);
        cs[pos] = (int)((f2h16(w) << 16) | (unsigned)s);
    }
}

// ---------------- dual aggregation, 128 cols, column-split (z = half) ----------------
// 8 groups of 8 lanes per wave; group handles one edge, 8 lanes x 16B = 64 cols.
__global__ __launch_bounds__(256) void dualagg128_kernel(
    const unsigned short* __restrict__ h1, const unsigned short* __restrict__ h2,
    const int* __restrict__ rp1, const int* __restrict__ cs1, const float* __restrict__ dv1,
    const int* __restrict__ rp2, const int* __restrict__ cs2, const float* __restrict__ dv2,
    const float* __restrict__ bias, unsigned short* __restrict__ o1,
    unsigned short* __restrict__ o2, int n) {
    const unsigned short* h;
    const int *rp, *cs;
    const float* dv;
    unsigned short* out;
    if (blockIdx.y == 0) { h = h1; rp = rp1; cs = cs1; dv = dv1; out = o1; }
    else                 { h = h2; rp = rp2; cs = cs2; dv = dv2; out = o2; }
    int wid = blockIdx.x * 4 + (threadIdx.x >> 6);
    if (wid >= n) return;
    int lane = threadIdx.x & 63;
    int grp = lane >> 3;
    int li = lane & 7;
    int colbase = (int)blockIdx.z * 64 + li * 8;
    float acc[8] = {0.f, 0.f, 0.f, 0.f, 0.f, 0.f, 0.f, 0.f};
    int e0 = rp[wid], e1 = rp[wid + 1];
    int e = e0 + grp;
    for (; e + 8 < e1; e += 16) {
        int va = cs[e], vb = cs[e + 8];
        float wa = h16f((unsigned)va >> 16); int sa = va & 0xFFFF;
        float wb = h16f((unsigned)vb >> 16); int sb = vb & 0xFFFF;
        int4 ra = *(const int4*)(h + (size_t)sa * 128 + colbase);
        int4 rb = *(const int4*)(h + (size_t)sb * 128 + colbase);
        acc8(acc, wa, ra);
        acc8(acc, wb, rb);
    }
    if (e < e1) {
        int va = cs[e];
        float wa = h16f((unsigned)va >> 16); int sa = va & 0xFFFF;
        int4 ra = *(const int4*)(h + (size_t)sa * 128 + colbase);
        acc8(acc, wa, ra);
    }
#pragma unroll
    for (int j = 0; j < 8; ++j) {
        acc[j] += __shfl_xor(acc[j], 8);
        acc[j] += __shfl_xor(acc[j], 16);
        acc[j] += __shfl_xor(acc[j], 32);
    }
    if (grp == 0) {
        float dn = dv[wid];
        float w = dn * dn;  // self-loop norm
        int4 rs = *(const int4*)(h + (size_t)wid * 128 + colbase);
        acc8(acc, w, rs);
        float4 b0 = *(const float4*)(bias + colbase);
        float4 b1 = *(const float4*)(bias + colbase + 4);
        acc[0] += b0.x; acc[1] += b0.y; acc[2] += b0.z; acc[3] += b0.w;
        acc[4] += b1.x; acc[5] += b1.y; acc[6] += b1.z; acc[7] += b1.w;
        int4 o;
        o.x = (int)((unsigned)f2bf(acc[0]) | ((unsigned)f2bf(acc[1]) << 16));
        o.y = (int)((unsigned)f2bf(acc[2]) | ((unsigned)f2bf(acc[3]) << 16));
        o.z = (int)((unsigned)f2bf(acc[4]) | ((unsigned)f2bf(acc[5]) << 16));
        o.w = (int)((unsigned)f2bf(acc[6]) | ((unsigned)f2bf(acc[7]) << 16));
        *(int4*)(out + (size_t)wid * 128 + colbase) = o;
    }
}

// ---------------- final aggregation (40 cols, float out), 16-lane groups ----------------
__global__ __launch_bounds__(256) void dualagg_final_kernel(
    const unsigned short* __restrict__ h1, const unsigned short* __restrict__ h2,
    const int* __restrict__ rp1, const int* __restrict__ cs1, const float* __restrict__ dv1,
    const int* __restrict__ rp2, const int* __restrict__ cs2, const float* __restrict__ dv2,
    const float* __restrict__ bias, float* __restrict__ o1, float* __restrict__ o2, int n) {
    constexpr int COLS = 40;
    constexpr int ACT = COLS / 8;   // 5
    const unsigned short* h;
    const int *rp, *cs;
    const float* dv;
    float* out;
    if (blockIdx.y == 0) { h = h1; rp = rp1; cs = cs1; dv = dv1; out = o1; }
    else                 { h = h2; rp = rp2; cs = cs2; dv = dv2; out = o2; }
    int wid = blockIdx.x * 4 + (threadIdx.x >> 6);
    if (wid >= n) return;
    int lane = threadIdx.x & 63;
    int grp = lane >> 4;
    int li = lane & 15;
    bool act = li < ACT;
    float acc[8] = {0.f, 0.f, 0.f, 0.f, 0.f, 0.f, 0.f, 0.f};
    int e0 = rp[wid], e1 = rp[wid + 1];
    int e = e0 + grp;
    for (; e + 4 < e1; e += 8) {
        int va = cs[e], vb = cs[e + 4];
        float wa = h16f((unsigned)va >> 16); int sa = va & 0xFFFF;
        float wb = h16f((unsigned)vb >> 16); int sb = vb & 0xFFFF;
        if (act) {
            int4 ra = *(const int4*)(h + (size_t)sa * COLS + li * 8);
            int4 rb = *(const int4*)(h + (size_t)sb * COLS + li * 8);
            acc8(acc, wa, ra);
            acc8(acc, wb, rb);
        }
    }
    if (e < e1) {
        int va = cs[e];
        float wa = h16f((unsigned)va >> 16); int sa = va & 0xFFFF;
        if (act) {
            int4 ra = *(const int4*)(h + (size_t)sa * COLS + li * 8);
            acc8(acc, wa, ra);
        }
    }
#pragma unroll
    for (int j = 0; j < 8; ++j) {
        acc[j] += __shfl_xor(acc[j], 16);
        acc[j] += __shfl_xor(acc[j], 32);
    }
    if (grp == 0 && act) {
        float dn = dv[wid];
        float w = dn * dn;  // self-loop norm
        int4 rs = *(const int4*)(h + (size_t)wid * COLS + li * 8);
        acc8(acc, w, rs);
        float4 b0 = ((const float4*)bias)[li * 2];
        float4 b1 = ((const float4*)bias)[li * 2 + 1];
        acc[0] += b0.x; acc[1] += b0.y; acc[2] += b0.z; acc[3] += b0.w;
        acc[4] += b1.x; acc[5] += b1.y; acc[6] += b1.z; acc[7] += b1.w;
        float* op = out + (size_t)wid * COLS + li * 8;
        *(float4*)op = make_float4(acc[0], acc[1], acc[2], acc[3]);
        *(float4*)(op + 4) = make_float4(acc[4], acc[5], acc[6], acc[7]);
    }
}

// ---------------- prep: Wm->Wt, Wi->hi/lo Wt1, zero gcount+ticks ----------------
__global__ __launch_bounds__(256) void prep_kernel(const float* __restrict__ Wm,
                                                   const float* __restrict__ Wi,
                                                   unsigned short* __restrict__ Wt,
                                                   unsigned short* __restrict__ Wt1,
                                                   int* __restrict__ zeros) {
    int b = blockIdx.x;
    int t = threadIdx.x;
    if (b < 128) {            // prepW: 2 layers x 16384
        int l = b >> 6;
        int o = (b & 63) * 256 + t;
        int kk = o & 31;
        int col = (o >> 5) & 127;
        int kc = o >> 12;
        int k = kc * 32 + kk;
        Wt[(size_t)l * 16384 + o] = f2bf(Wm[(size_t)l * 16384 + (size_t)k * 128 + col]);
    } else if (b < 256) {     // prepW1: 32768 hi/lo
        int o = (b - 128) * 256 + t;
        int kk = o & 31;
        int col = (o >> 5) & 63;
        int kc = (o >> 11) & 3;
        int hsel = (o >> 13) & 1;
        int s = (o >> 14) & 1;
        float w = Wi[(size_t)s * 8192 + (size_t)(kc * 32 + kk) * 64 + col];
        unsigned short hi = f2bf(w);
        Wt1[o] = hsel ? f2bf(w - bf2f(hi)) : hi;
    } else {                  // zero gcount (16) + tickets (3) region
        if (t < 32) zeros[t] = 0;
    }
}

// ---------------- Layer-1 MFMA GEMM, LDS-free (fp32-accurate hi/lo split) ----------------
__global__ __launch_bounds__(256) void gemm_l1_kernel(
    const float* __restrict__ x1a, const float* __restrict__ x1b, const float* __restrict__ x2a,
    const float* __restrict__ x2b, const unsigned short* __restrict__ Wt1,
    unsigned short* __restrict__ H1, unsigned short* __restrict__ H2, int nrows) {
    const float* X = (blockIdx.y == 0) ? x1a : (blockIdx.y == 1) ? x1b
                     : (blockIdx.y == 2) ? x2a : x2b;
    int slice = blockIdx.y & 1;
    unsigned short* Y = (blockIdx.y < 2) ? H1 : H2;
    int ocol = slice * 64;
    int tid = threadIdx.x;
    int row0 = blockIdx.x * 64;
    int wave = tid >> 6, lane = tid & 63;
    int m = lane & 15, quad = lane >> 4;
    int arow = row0 + wave * 16 + m;
    bool rv = arow < nrows;
    const float* xp = X + (size_t)arow * DFEAT;
    const unsigned short* Whp = Wt1 + (size_t)slice * 16384;
    const unsigned short* Wlp = Whp + 8192;
    f32x4 acc[4];
#pragma unroll
    for (int i = 0; i < 4; ++i) acc[i] = (f32x4){0.f, 0.f, 0.f, 0.f};
#pragma unroll
    for (int kc = 0; kc < 4; ++kc) {
        float4 f0 = make_float4(0.f, 0.f, 0.f, 0.f);
        float4 f1 = make_float4(0.f, 0.f, 0.f, 0.f);
        if (rv) {
            f0 = *(const float4*)(xp + kc * 32 + quad * 8);
            f1 = *(const float4*)(xp + kc * 32 + quad * 8 + 4);
        }
        float fs[8] = {f0.x, f0.y, f0.z, f0.w, f1.x, f1.y, f1.z, f1.w};
        bf16x8 ah, al;
#pragma unroll
        for (int j = 0; j < 8; ++j) {
            unsigned short hh = f2bf(fs[j]);
            ah[j] = (short)hh;
            al[j] = (short)f2bf(fs[j] - bf2f(hh));
        }
#pragma unroll
        for (int ct = 0; ct < 4; ++ct) {
            int wo = kc * 2048 + (ct * 16 + m) * 32 + quad * 8;
            bf16x8 bh = *(const bf16x8*)(Whp + wo);
            bf16x8 bl = *(const bf16x8*)(Wlp + wo);
            acc[ct] = __builtin_amdgcn_mfma_f32_16x16x32_bf16(ah, bh, acc[ct], 0, 0, 0);
            acc[ct] = __builtin_amdgcn_mfma_f32_16x16x32_bf16(al, bh, acc[ct], 0, 0, 0);
            acc[ct] = __builtin_amdgcn_mfma_f32_16x16x32_bf16(ah, bl, acc[ct], 0, 0, 0);
        }
    }
#pragma unroll
    for (int ct = 0; ct < 4; ++ct) {
#pragma unroll
        for (int i = 0; i < 4; ++i) {
            int gr = row0 + wave * 16 + quad * 4 + i;
            if (gr < nrows) Y[(size_t)gr * DFEAT + ocol + ct * 16 + m] = f2bf(acc[ct][i]);
        }
    }
}

// ---------------- MFMA fused GEMM (128->128): x = w1*relu(bn(A)) + w2*relu(bn(B)) ----------------
__global__ __launch_bounds__(256) void gemm_mfma_kernel(
    const unsigned short* __restrict__ Abf, const unsigned short* __restrict__ Bbf,
    const float* __restrict__ ss, const float* __restrict__ wout,
    const unsigned short* __restrict__ Wt, unsigned short* __restrict__ Y, int nrows) {
    __shared__ unsigned short Xs[64 * 128];
    int tid = threadIdx.x;
    int row0 = blockIdx.x * 64;
    int wave = tid >> 6, lane = tid & 63;
    int m = lane & 15, quad = lane >> 4;
    float w1 = wout[0], w2 = wout[1];
    for (int u = tid; u < 1024; u += 256) {
        int r = u >> 4;
        int col0 = (u & 15) * 8;
        int gr = row0 + r;
        int swz = (r & 7) << 3;
        if (gr < nrows) {
#pragma unroll
            for (int hh = 0; hh < 2; ++hh) {
                int c = col0 + hh * 4;
                float4 fa = bf4tof4(*(const ushort4*)(Abf + (size_t)gr * 128 + c));
                float4 fb = bf4tof4(*(const ushort4*)(Bbf + (size_t)gr * 128 + c));
                float4 sa = *(const float4*)(ss + c);
                float4 ha = *(const float4*)(ss + 128 + c);
                float4 sb = *(const float4*)(ss + 256 + c);
                float4 hb = *(const float4*)(ss + 384 + c);
                ushort4 o;
                o.x = f2bf(w1 * fmaxf(fmaf(fa.x, sa.x, ha.x), 0.f) +
                           w2 * fmaxf(fmaf(fb.x, sb.x, hb.x), 0.f));
                o.y = f2bf(w1 * fmaxf(fmaf(fa.y, sa.y, ha.y), 0.f) +
                           w2 * fmaxf(fmaf(fb.y, sb.y, hb.y), 0.f));
                o.z = f2bf(w1 * fmaxf(fmaf(fa.z, sa.z, ha.z), 0.f) +
                           w2 * fmaxf(fmaf(fb.z, sb.z, hb.z), 0.f));
                o.w = f2bf(w1 * fmaxf(fmaf(fa.w, sa.w, ha.w), 0.f) +
                           w2 * fmaxf(fmaf(fb.w, sb.w, hb.w), 0.f));
                *(ushort4*)&Xs[r * 128 + (c ^ swz)] = o;
            }
        } else {
            ushort4 z = {0, 0, 0, 0};
            *(ushort4*)&Xs[r * 128 + (col0 ^ swz)] = z;
            *(ushort4*)&Xs[r * 128 + ((col0 + 4) ^ swz)] = z;
        }
    }
    __syncthreads();
    f32x4 acc[8];
#pragma unroll
    for (int i = 0; i < 8; ++i) acc[i] = (f32x4){0.f, 0.f, 0.f, 0.f};
    int arow = wave * 16 + m;
#pragma unroll
    for (int kc = 0; kc < 4; ++kc) {
        int ac = (kc * 32 + quad * 8) ^ ((arow & 7) << 3);
        bf16x8 a = *(const bf16x8*)&Xs[arow * 128 + ac];
#pragma unroll
        for (int ct = 0; ct < 8; ++ct) {
            const unsigned short* bp = Wt + ((size_t)(kc * 128 + ct * 16 + m) * 32) + quad * 8;
            bf16x8 b = *(const bf16x8*)bp;
            acc[ct] = __builtin_amdgcn_mfma_f32_16x16x32_bf16(a, b, acc[ct], 0, 0, 0);
        }
    }
#pragma unroll
    for (int ct = 0; ct < 8; ++ct) {
#pragma unroll
        for (int i = 0; i < 4; ++i) {
            int gr = row0 + wave * 16 + quad * 4 + i;
            if (gr < nrows) Y[(size_t)gr * 128 + ct * 16 + m] = f2bf(acc[ct][i]);
        }
    }
}

// ---------------- VALU fused GEMM (final 128->40) ----------------
template <int CG, int RPT>
__global__ __launch_bounds__(256) void gemm_fused_kernel(
    const unsigned short* __restrict__ Abf, const unsigned short* __restrict__ Bbf,
    const float* __restrict__ ss, const float* __restrict__ wout, const float* __restrict__ W,
    unsigned short* __restrict__ Y, int nrows, int fout, int ostride) {
    __shared__ float Ws[32][CG * 4];
    __shared__ float Xs[64][33];
    int tid = threadIdx.x;
    int row0 = blockIdx.x * 64;
    int cg = tid % CG;
    int rg = tid / CG;
    float w1 = wout[0], w2 = wout[1];
    float4 acc[RPT];
#pragma unroll
    for (int i = 0; i < RPT; ++i) acc[i] = make_float4(0.f, 0.f, 0.f, 0.f);
    for (int kc = 0; kc < 4; ++kc) {
        for (int i = tid; i < 32 * CG; i += 256) {
            int r = i / CG, c = i % CG;
            float4 w;
            if ((c * 4 + 3) < fout) {
                w = *(const float4*)(W + (size_t)(kc * 32 + r) * fout + c * 4);
            } else {
                float t0 = (c * 4 + 0) < fout ? W[(size_t)(kc * 32 + r) * fout + c * 4 + 0] : 0.f;
                float t1 = (c * 4 + 1) < fout ? W[(size_t)(kc * 32 + r) * fout + c * 4 + 1] : 0.f;
                float t2 = (c * 4 + 2) < fout ? W[(size_t)(kc * 32 + r) * fout + c * 4 + 2] : 0.f;
                float t3 = (c * 4 + 3) < fout ? W[(size_t)(kc * 32 + r) * fout + c * 4 + 3] : 0.f;
                w = make_float4(t0, t1, t2, t3);
            }
            *(float4*)&Ws[r][c * 4] = w;
        }
        for (int i = tid; i < 64 * 8; i += 256) {
            int r = i / 8, c = i % 8;
            int gr = row0 + r;
            int col0 = kc * 32 + c * 4;
            float4 v = make_float4(0.f, 0.f, 0.f, 0.f);
            if (gr < nrows) {
                float4 a = bf4tof4(*(const ushort4*)(Abf + (size_t)gr * DFEAT + col0));
                float4 b = bf4tof4(*(const ushort4*)(Bbf + (size_t)gr * DFEAT + col0));
                float4 scA = *(const float4*)(ss + col0);
                float4 shA = *(const float4*)(ss + DFEAT + col0);
                float4 scB = *(const float4*)(ss + 2 * DFEAT + col0);
                float4 shB = *(const float4*)(ss + 3 * DFEAT + col0);
                v.x = w1 * fmaxf(fmaf(a.x, scA.x, shA.x), 0.f) +
                      w2 * fmaxf(fmaf(b.x, scB.x, shB.x), 0.f);
                v.y = w1 * fmaxf(fmaf(a.y, scA.y, shA.y), 0.f) +
                      w2 * fmaxf(fmaf(b.y, scB.y, shB.y), 0.f);
                v.z = w1 * fmaxf(fmaf(a.z, scA.z, shA.z), 0.f) +
                      w2 * fmaxf(fmaf(b.z, scB.z, shB.z), 0.f);
                v.w = w1 * fmaxf(fmaf(a.w, scA.w, shA.w), 0.f) +
                      w2 * fmaxf(fmaf(b.w, scB.w, shB.w), 0.f);
            }
            Xs[r][c * 4 + 0] = v.x;
            Xs[r][c * 4 + 1] = v.y;
            Xs[r][c * 4 + 2] = v.z;
            Xs[r][c * 4 + 3] = v.w;
        }
        __syncthreads();
#pragma unroll
        for (int k = 0; k < 32; ++k) {
            float4 w = *(float4*)&Ws[k][cg * 4];
#pragma unroll
            for (int i = 0; i < RPT; ++i) {
                float a = Xs[rg * RPT + i][k];
                acc[i].x = fmaf(a, w.x, acc[i].x);
                acc[i].y = fmaf(a, w.y, acc[i].y);
                acc[i].z = fmaf(a, w.z, acc[i].z);
                acc[i].w = fmaf(a, w.w, acc[i].w);
            }
        }
        __syncthreads();
    }
    if (cg * 4 < fout) {
#pragma unroll
        for (int i = 0; i < RPT; ++i) {
            int r = row0 + rg * RPT + i;
            if (r < nrows) {
                ushort4 o;
                o.x = f2bf(acc[i].x); o.y = f2bf(acc[i].y);
                o.z = f2bf(acc[i].z); o.w = f2bf(acc[i].w);
                *(ushort4*)(Y + (size_t)r * ostride + cg * 4) = o;
            }
        }
    }
}

// ---------------- fused BN stats + gate prep (atomic-ticket last block) ----------------
__global__ __launch_bounds__(256) void stats2g_kernel(
    const unsigned short* __restrict__ A, const unsigned short* __restrict__ B,
    float* __restrict__ stats, int nrows,
    const float* __restrict__ gamma, const float* __restrict__ beta,
    const float* __restrict__ gwA, const float* __restrict__ gbA,
    const float* __restrict__ gwB, const float* __restrict__ gbB,
    float* __restrict__ ss, float* __restrict__ wout, unsigned* __restrict__ tick) {
    __shared__ float red1[256];
    __shared__ float red2[256];
    int t = threadIdx.x;
    {
        int col = t & 127;
        int rg = t >> 7;
        const unsigned short* src = (blockIdx.y == 0) ? A : B;
        float* st = stats + (size_t)blockIdx.y * 256;
        int r0 = blockIdx.x * 128 + rg * 64;
        int r1 = min(r0 + 64, nrows);
        float s = 0.f, s2 = 0.f;
        for (int r = r0; r < r1; ++r) {
            float v = bf2f(src[(size_t)r * DFEAT + col]);
            s += v;
            s2 = fmaf(v, v, s2);
        }
        red1[t] = s;
        red2[t] = s2;
        __syncthreads();
        if (t < 128) {
            atomicAdd(&st[col], red1[t] + red1[t + 128]);
            atomicAdd(&st[DFEAT + col], red2[t] + red2[t + 128]);
        }
    }
    // ticket: last block does gate prep
    __threadfence();
    __shared__ int amlast;
    __syncthreads();
    if (t == 0) {
        unsigned v = atomicAdd(tick, 1u);
        amlast = (v == gridDim.x * gridDim.y - 1) ? 1 : 0;
    }
    __syncthreads();
    if (!amlast) return;
    __shared__ float red[128];
    __shared__ float dotA_s;
    float invN = 1.f / (float)nrows;
    float scA = 0.f, shA = 0.f, scB = 0.f, shB = 0.f;
    if (t < 128) {
        // stats were written by ATOMICS -> re-read via atomic for coherence
        float sA = atomicAdd(&stats[t], 0.f);
        float s2A = atomicAdd(&stats[DFEAT + t], 0.f);
        float sB = atomicAdd(&stats[256 + t], 0.f);
        float s2B = atomicAdd(&stats[256 + DFEAT + t], 0.f);
        float meanA = sA * invN;
        float varA = s2A * invN - meanA * meanA;
        scA = gamma[t] * rsqrtf(varA + 1e-5f);
        shA = beta[t] - meanA * scA;
        ss[t] = scA;
        ss[DFEAT + t] = shA;
        float meanB = sB * invN;
        float varB = s2B * invN - meanB * meanB;
        scB = gamma[t] * rsqrtf(varB + 1e-5f);
        shB = beta[t] - meanB * scB;
        ss[2 * DFEAT + t] = scB;
        ss[3 * DFEAT + t] = shB;
        stats[t] = 0.f;
        stats[DFEAT + t] = 0.f;
        stats[256 + t] = 0.f;
        stats[256 + DFEAT + t] = 0.f;
        float av = fmaxf(fmaf(bf2f(A[(size_t)(nrows - 1) * DFEAT + t]), scA, shA), 0.f);
        red[t] = av * gwA[t];
    }
    __syncthreads();
    for (int s = 64; s > 0; s >>= 1) {
        if (t < s) red[t] += red[t + s];
        __syncthreads();
    }
    if (t == 0) dotA_s = red[0];
    __syncthreads();
    if (t < 128) {
        float bv = fmaxf(fmaf(bf2f(B[(size_t)(nrows - 1) * DFEAT + t]), scB, shB), 0.f);
        red[t] = bv * gwB[t];
    }
    __syncthreads();
    for (int s = 64; s > 0; s >>= 1) {
        if (t < s) red[t] += red[t + s];
        __syncthreads();
    }
    if (t == 0) {
        float s1 = 1.f / (1.f + expf(-(dotA_s + gbA[0])));
        float s2 = 1.f / (1.f + expf(-(red[0] + gbB[0])));
        float tt = s1 + s2;
        wout[0] = s1 / tt;
        wout[1] = s2 / tt;
    }
}

__global__ __launch_bounds__(64) void gate_final_kernel(
    const float* __restrict__ p1, const float* __restrict__ p2,
    const float* __restrict__ w1v, const float* __restrict__ b1,
    const float* __restrict__ w2v, const float* __restrict__ b2,
    float* __restrict__ wout, int nrows, int nclass) {
    __shared__ float red[64];
    __shared__ float dot1_s;
    int t = threadIdx.x;
    float v = (t < nclass) ? p1[(size_t)(nrows - 1) * nclass + t] * w1v[t] : 0.f;
    red[t] = v;
    __syncthreads();
    for (int s = 32; s > 0; s >>= 1) {
        if (t < s) red[t] += red[t + s];
        __syncthreads();
    }
    if (t == 0) dot1_s = red[0];
    __syncthreads();
    v = (t < nclass) ? p2[(size_t)(nrows - 1) * nclass + t] * w2v[t] : 0.f;
    red[t] = v;
    __syncthreads();
    for (int s = 32; s > 0; s >>= 1) {
        if (t < s) red[t] += red[t + s];
        __syncthreads();
    }
    if (t == 0) {
        float s1 = 1.f / (1.f + expf(-(dot1_s + b1[0])));
        float s2 = 1.f / (1.f + expf(-(red[0] + b2[0])));
        float tt = s1 + s2;
        wout[0] = s1 / tt;
        wout[1] = s2 / tt;
    }
}

__global__ __launch_bounds__(256) void mix_kernel(const float* __restrict__ p1,
                                                  const float* __restrict__ p2,
                                                  const float* __restrict__ wout,
                                                  float* __restrict__ o, int n4) {
    int idx = blockIdx.x * blockDim.x + threadIdx.x;
    if (idx >= n4) return;
    float w1 = wout[0], w2 = wout[1];
    float4 a = *(const float4*)(p1 + (size_t)idx * 4);
    float4 b = *(const float4*)(p2 + (size_t)idx * 4);
    float4 r = make_float4(w1 * a.x + w2 * b.x, w1 * a.y + w2 * b.y, w1 * a.z + w2 * b.z,
                           w1 * a.w + w2 * b.w);
    *(float4*)(o + (size_t)idx * 4) = r;
}

extern "C" void kernel_launch(void* const* d_in, const int* in_sizes, int n_in, void* d_out,
                              int out_size, void* d_ws, size_t ws_size, hipStream_t stream) {
    (void)n_in; (void)out_size; (void)ws_size;
    const int N = in_sizes[0] / DFEAT;        // 50000
    const int E = in_sizes[4] / 2;            // 800000
    const int NC = in_sizes[15];              // 40

    const float* x1a = (const float*)d_in[0];
    const float* x1b = (const float*)d_in[1];
    const float* x2a = (const float*)d_in[2];
    const float* x2b = (const float*)d_in[3];
    const int* ei1 = (const int*)d_in[4];
    const int* ei2 = (const int*)d_in[5];
    const float* Wi = (const float*)d_in[6];
    const float* bi = (const float*)d_in[7];
    const float* gi = (const float*)d_in[8];
    const float* bei = (const float*)d_in[9];
    const float* Wm = (const float*)d_in[10];
    const float* bm = (const float*)d_in[11];
    const float* gm = (const float*)d_in[12];
    const float* bem = (const float*)d_in[13];
    const float* Wf = (const float*)d_in[14];
    const float* bf = (const float*)d_in[15];
    const float* fc1w1_W = (const float*)d_in[16];
    const float* fc1w1_b = (const float*)d_in[17];
    const float* fc1w2_W = (const float*)d_in[18];
    const float* fc1w2_b = (const float*)d_in[19];
    const float* aws_w1_W = (const float*)d_in[20];
    const float* aws_w1_b = (const float*)d_in[21];
    const float* aws_w2_W = (const float*)d_in[22];
    const float* aws_w2_b = (const float*)d_in[23];
    const float* fcw1_W = (const float*)d_in[24];
    const float* fcw1_b = (const float*)d_in[25];
    const float* fcw2_W = (const float*)d_in[26];
    const float* fcw2_b = (const float*)d_in[27];

    char* ws = (char*)d_ws;
    size_t off = 0;
    auto alloc = [&](size_t bytes) -> char* {
        char* p = ws + off;
        off += (bytes + 255) & ~(size_t)255;
        return p;
    };
    unsigned short* A = (unsigned short*)alloc((size_t)N * DFEAT * 2);
    unsigned short* B = (unsigned short*)alloc((size_t)N * DFEAT * 2);
    unsigned short* H1 = (unsigned short*)alloc((size_t)N * DFEAT * 2);
    unsigned short* H2 = (unsigned short*)alloc((size_t)N * DFEAT * 2);
    int* rp1 = (int*)alloc((size_t)(N + 1) * 4);
    int* rp2 = (int*)alloc((size_t)(N + 1) * 4);
    int* cnt1 = (int*)alloc((size_t)N * 4);
    int* cnt2 = (int*)alloc((size_t)N * 4);
    float* dv1 = (float*)alloc((size_t)N * 4);
    float* dv2 = (float*)alloc((size_t)N * 4);
    int* cs1 = (int*)alloc((size_t)E * 4);
    int* cs2 = (int*)alloc((size_t)E * 4);
    int* stg = (int*)alloc((size_t)2 * NRMAX * SCAP * 4);             // 10.2 MB
    int* baseB = (int*)alloc(((size_t)2 * NRMAX * SUBS << RSH) * 4);  // 16.8 MB
    int* gcount = (int*)alloc(32 * 4);        // 16 counts + 3 tickets (+pad)
    unsigned* tick = (unsigned*)(gcount + 24);
    unsigned short* Wt = (unsigned short*)alloc((size_t)2 * 16384 * 2);
    unsigned short* Wt1 = (unsigned short*)alloc((size_t)32768 * 2);  // 64 KB
    float* stats = (float*)alloc(2048);
    float* ssbuf = (float*)alloc(2048);
    float* wout = (float*)alloc(256);
    int nb = (N + 255) / 256;                 // 196 (scanB/writerp blocking)
    int* bsums = (int*)alloc((size_t)2 * nb * 4);

    const int* src1 = ei1;
    const int* dst1 = ei1 + E;
    const int* src2 = ei2;
    const int* dst2 = ei2 + E;

    int nr = (N + RSZ - 1) >> RSH;            // 7
    int gemmbl = (N + 63) / 64;
    dim3 pagrid((E + EPA - 1) / EPA, 2);      // 391 x 2
    dim3 rsgrid(nr * SUBS, 2);                // 112 x 2
    dim3 nodegrid(nb, 2);
    dim3 agggrid((N + 3) / 4, 2, 2);          // z = column half
    dim3 aggfgrid((N + 3) / 4, 2);
    dim3 statgrid((N + 127) / 128, 2);
    dim3 l1grid(gemmbl, 4);

    // ---- prep + CSR build (two-level counting sort, LDS atomics only) ----
    prep_kernel<<<257, 256, 0, stream>>>(Wm, Wi, Wt, Wt1, gcount);
    partA_kernel<<<pagrid, 256, 0, stream>>>(src1, dst1, src2, dst2, stg, gcount, E, nr);
    histB_kernel<<<rsgrid, 256, 0, stream>>>(stg, gcount, baseB, nr);
    scanB_kernel<<<nodegrid, 256, 0, stream>>>(baseB, cnt1, cnt2, bsums, N, nb);
    scansums_kernel<<<1, 64, 0, stream>>>(bsums, nb, rp1, rp2, N, E, stats);
    writerp_kernel<<<nodegrid, 256, 0, stream>>>(cnt1, cnt2, bsums, rp1, rp2, dv1, dv2, N, nb);
    fillC_kernel<<<rsgrid, 256, 0, stream>>>(stg, gcount, baseB, rp1, rp2, dv1, dv2,
                                             cs1, cs2, N, nr);

    // ---- Layer 1 ----
    gemm_l1_kernel<<<l1grid, 256, 0, stream>>>(x1a, x1b, x2a, x2b, Wt1, H1, H2, N);
    dualagg128_kernel<<<agggrid, 256, 0, stream>>>(H1, H2, rp1, cs1, dv1, rp2, cs2, dv2,
                                                   bi, A, B, N);
    stats2g_kernel<<<statgrid, 256, 0, stream>>>(A, B, stats, N, gi, bei, fc1w1_W, fc1w1_b,
                                                 fc1w2_W, fc1w2_b, ssbuf, wout, tick);

    // ---- Middle layer 0 ----
    gemm_mfma_kernel<<<gemmbl, 256, 0, stream>>>(A, B, ssbuf, wout, Wt, H1, N);
    dualagg128_kernel<<<agggrid, 256, 0, stream>>>(H1, H1, rp1, cs1, dv1, rp2, cs2, dv2,
                                                   bm, A, B, N);
    stats2g_kernel<<<statgrid, 256, 0, stream>>>(A, B, stats, N, gm, bem, aws_w1_W, aws_w1_b,
                                                 aws_w2_W, aws_w2_b, ssbuf, wout, tick + 1);

    // ---- Middle layer 1 ----
    gemm_mfma_kernel<<<gemmbl, 256, 0, stream>>>(A, B, ssbuf, wout, Wt + 16384, H1, N);
    dualagg128_kernel<<<agggrid, 256, 0, stream>>>(H1, H1, rp1, cs1, dv1, rp2, cs2, dv2,
                                                   bm + 128, A, B, N);
    stats2g_kernel<<<statgrid, 256, 0, stream>>>(A, B, stats, N, gm + 128, bem + 128,
                                                 aws_w1_W + 128, aws_w1_b + 1, aws_w2_W + 128,
                                                 aws_w2_b + 1, ssbuf, wout, tick + 2);

    // ---- Final layer ----
    float* out0 = (float*)d_out;
    float* p1 = out0 + (size_t)N * NC;
    float* p2 = out0 + (size_t)2 * N * NC;
    gemm_fused_kernel<16, 4><<<gemmbl, 256, 0, stream>>>(A, B, ssbuf, wout, Wf, H2, N, NC, NC);
    dualagg_final_kernel<<<aggfgrid, 256, 0, stream>>>(H2, H2, rp1, cs1, dv1, rp2, cs2, dv2,
                                                       bf, p1, p2, N);
    gate_final_kernel<<<1, 64, 0, stream>>>(p1, p2, fcw1_W, fcw1_b, fcw2_W, fcw2_b, wout, N, NC);
    mix_kernel<<<(N * NC / 4 + 255) / 256, 256, 0, stream>>>(p1, p2, wout, out0, N * NC / 4);
}

// Round 9
// 770.427 us; speedup vs baseline: 1.1182x; 1.1182x over previous
//
#include <hip/hip_runtime.h>
#include <hip/hip_fp16.h>

// CLAGCN forward on MI355X.
// R1-R13: counting-sort CSR build, MFMA GEMMs, LDS-free l1, 16-lane dualagg.
// R14 (FAILED, 862us): dualagg column-split doubled issue overhead (VALU 56->72%,
//     61->88us) and scansums' single-thread scan over nb=196 blocks added ~40us
//     serial latency. FETCH did drop 163->131MB — L2 theory right, cost wrong.
// R15: revert dualagg to R13 16-lane full-row form (256B-coalesced gathers);
//     parallel Hillis-Steele scansums (nb<=256); keep R14's dispatch fusions
//     (prep fusion, scanB+bsums fold, stats2g atomic-ticket last-block).

#define DFEAT 128

typedef __attribute__((ext_vector_type(8))) short bf16x8;
typedef __attribute__((ext_vector_type(4))) float f32x4;

__device__ __forceinline__ unsigned short f2bf(float f) {
    unsigned u = __float_as_uint(f);
    u += 0x7fffu + ((u >> 16) & 1u);
    return (unsigned short)(u >> 16);
}
__device__ __forceinline__ float bf2f(unsigned short u) {
    return __uint_as_float((unsigned)u << 16);
}
__device__ __forceinline__ unsigned f2h16(float f) {
    return (unsigned)__half_as_ushort(__float2half(f));
}
__device__ __forceinline__ float h16f(unsigned u) {
    return __half2float(__ushort_as_half((unsigned short)u));
}
__device__ __forceinline__ float4 bf4tof4(ushort4 u) {
    return make_float4(__uint_as_float((unsigned)u.x << 16),
                       __uint_as_float((unsigned)u.y << 16),
                       __uint_as_float((unsigned)u.z << 16),
                       __uint_as_float((unsigned)u.w << 16));
}
// accumulate 8 bf16 (packed in int4) * w into acc[8]
__device__ __forceinline__ void acc8(float* acc, float w, int4 r) {
    int vs[4] = {r.x, r.y, r.z, r.w};
#pragma unroll
    for (int q = 0; q < 4; ++q) {
        float lo = __uint_as_float((unsigned)vs[q] << 16);
        float hi = __uint_as_float((unsigned)vs[q] & 0xffff0000u);
        acc[q * 2] = fmaf(w, lo, acc[q * 2]);
        acc[q * 2 + 1] = fmaf(w, hi, acc[q * 2 + 1]);
    }
}

// ---------------- two-level counting-sort CSR build ----------------
constexpr int RSH = 13;        // range shift -> 8192 nodes per range
constexpr int RSZ = 8192;
constexpr int NRMAX = 8;       // max ranges (N <= 65536)
constexpr int EPA = 2048;      // edges per partition block
constexpr int SUBS = 16;       // sub-slices per range for hist/fill
constexpr int SCAP = 160000;   // stream capacity per (graph, range)

__global__ __launch_bounds__(256) void partA_kernel(
    const int* __restrict__ src1, const int* __restrict__ dst1,
    const int* __restrict__ src2, const int* __restrict__ dst2,
    int* __restrict__ stg, int* __restrict__ gcount, int E, int nr) {
    int g = blockIdx.y;
    const int* src = g ? src2 : src1;
    const int* dst = g ? dst2 : dst1;
    __shared__ int buf[EPA];
    __shared__ int buf2[EPA];
    __shared__ int cnt8[NRMAX + 1], pre8[NRMAX + 1], base8[NRMAX];
    int t = threadIdx.x;
    if (t < NRMAX) cnt8[t] = 0;
    __syncthreads();
    int e0 = blockIdx.x * EPA;
    int e1 = min(e0 + EPA, E);
    int ec = e1 - e0;
    for (int i = e0 + t; i < e1; i += 256) {
        int d = dst[i];
        int s = src[i];
        buf[i - e0] = (d << 16) | s;
        atomicAdd(&cnt8[d >> RSH], 1);
    }
    __syncthreads();
    if (t == 0) {
        int run = 0;
        for (int r = 0; r < nr; ++r) { pre8[r] = run; run += cnt8[r]; }
        pre8[nr] = run;
    }
    __syncthreads();
    if (t < nr) {
        base8[t] = atomicAdd(&gcount[g * NRMAX + t], cnt8[t]);
        cnt8[t] = 0;
    }
    __syncthreads();
    for (int j = t; j < ec; j += 256) {
        int v = buf[j];
        int d = (unsigned)v >> 16;
        int r = d >> RSH;
        int p = pre8[r] + atomicAdd(&cnt8[r], 1);
        buf2[p] = ((d & (RSZ - 1)) << 16) | (v & 0xFFFF);
    }
    __syncthreads();
    for (int j = t; j < ec; j += 256) {
        int r = 0;
        while (j >= pre8[r + 1]) ++r;
        int gpos = base8[r] + (j - pre8[r]);
        if (gpos < SCAP) stg[((size_t)g * NRMAX + r) * SCAP + gpos] = buf2[j];
    }
}

__global__ __launch_bounds__(256) void histB_kernel(
    const int* __restrict__ stg, const int* __restrict__ gcount,
    int* __restrict__ baseB, int nr) {
    int g = blockIdx.y;
    int r = blockIdx.x / SUBS;
    int sub = blockIdx.x % SUBS;
    __shared__ int hist[RSZ];
    int t = threadIdx.x;
    for (int i = t; i < RSZ; i += 256) hist[i] = 0;
    __syncthreads();
    int len = min(gcount[g * NRMAX + r], SCAP);
    int seg = (len + SUBS - 1) / SUBS;
    int e0 = sub * seg, e1 = min(e0 + seg, len);
    const int* sp = stg + ((size_t)g * NRMAX + r) * SCAP;
    for (int i = e0 + t; i < e1; i += 256) atomicAdd(&hist[(unsigned)sp[i] >> 16], 1);
    __syncthreads();
    int* bp = baseB + (((size_t)(g * NRMAX + r) * SUBS + sub) << RSH);
    for (int i = t; i < RSZ; i += 256) bp[i] = hist[i];
}

// scanB: per-node exclusive prefix over subs -> cnt, PLUS block total -> bsums
__global__ __launch_bounds__(256) void scanB_kernel(
    int* __restrict__ baseB, int* __restrict__ cnt1, int* __restrict__ cnt2,
    int* __restrict__ bsums, int n, int nb) {
    int node = blockIdx.x * 256 + threadIdx.x;
    int g = blockIdx.y;
    int t = threadIdx.x;
    int run = 0;
    if (node < n) {
        int r = node >> RSH, dloc = node & (RSZ - 1);
        int* p = baseB + (((size_t)(g * NRMAX + r) * SUBS) << RSH) + dloc;
#pragma unroll
        for (int s = 0; s < SUBS; ++s) {
            int v = p[(size_t)s << RSH];
            p[(size_t)s << RSH] = run;
            run += v;
        }
        (g ? cnt2 : cnt1)[node] = run;
    }
    __shared__ int red[256];
    red[t] = run;
    __syncthreads();
    for (int o = 128; o > 0; o >>= 1) {
        if (t < o) red[t] += red[t + o];
        __syncthreads();
    }
    if (t == 0) bsums[(size_t)g * nb + blockIdx.x] = red[0];
}

// parallel exclusive scan of bsums (nb <= 256) for both graphs; zero stats.
__global__ __launch_bounds__(256) void scansums_kernel(
    int* __restrict__ bs, int nb, int* __restrict__ rp1, int* __restrict__ rp2,
    int n, int E, float* __restrict__ stats) {
    __shared__ int red[256];
    int t = threadIdx.x;
    for (int g = 0; g < 2; ++g) {
        int v = (t < nb) ? bs[(size_t)g * nb + t] : 0;
        red[t] = v;
        __syncthreads();
        for (int o = 1; o < 256; o <<= 1) {
            int x = (t >= o) ? red[t - o] : 0;
            __syncthreads();
            red[t] += x;
            __syncthreads();
        }
        if (t < nb) bs[(size_t)g * nb + t] = red[t] - v;  // exclusive
        __syncthreads();
    }
    if (t < 2) (t ? rp2 : rp1)[n] = E;
    for (int i = t; i < 512; i += 256) stats[i] = 0.f;
}

// writerp: 256 nodes/block (matches scanB blocking), in-block scan
__global__ __launch_bounds__(256) void writerp_kernel(
    const int* __restrict__ c1, const int* __restrict__ c2, const int* __restrict__ bs,
    int* __restrict__ rp1, int* __restrict__ rp2,
    float* __restrict__ dv1, float* __restrict__ dv2, int n, int nb) {
    const int* c = blockIdx.y ? c2 : c1;
    int* rp = blockIdx.y ? rp2 : rp1;
    float* dv = blockIdx.y ? dv2 : dv1;
    int t = threadIdx.x;
    int node = blockIdx.x * 256 + t;
    int v = (node < n) ? c[node] : 0;
    __shared__ int red[256];
    red[t] = v;
    __syncthreads();
    for (int o = 1; o < 256; o <<= 1) {
        int x = (t >= o) ? red[t - o] : 0;
        __syncthreads();
        red[t] += x;
        __syncthreads();
    }
    if (node < n) {
        int run = bs[(size_t)blockIdx.y * nb + blockIdx.x] + red[t] - v;
        rp[node] = run;
        dv[node] = rsqrtf((float)(v + 1));  // +1 self-loop
    }
}

__global__ __launch_bounds__(256) void fillC_kernel(
    const int* __restrict__ stg, const int* __restrict__ gcount,
    const int* __restrict__ baseB,
    const int* __restrict__ rp1, const int* __restrict__ rp2,
    const float* __restrict__ dv1, const float* __restrict__ dv2,
    int* __restrict__ cs1, int* __restrict__ cs2, int n, int nr) {
    int g = blockIdx.y;
    int r = blockIdx.x / SUBS;
    int sub = blockIdx.x % SUBS;
    const int* rp = g ? rp2 : rp1;
    const float* dv = g ? dv2 : dv1;
    int* cs = g ? cs2 : cs1;
    __shared__ int off[RSZ];
    int t = threadIdx.x;
    int r0 = r << RSH;
    int rn = min(RSZ, n - r0);
    if (rn <= 0) return;
    const int* bp = baseB + (((size_t)(g * NRMAX + r) * SUBS + sub) << RSH);
    for (int i = t; i < rn; i += 256) off[i] = bp[i] + rp[r0 + i];
    __syncthreads();
    int len = min(gcount[g * NRMAX + r], SCAP);
    int seg = (len + SUBS - 1) / SUBS;
    int e0 = sub * seg, e1 = min(e0 + seg, len);
    const int* sp = stg + ((size_t)g * NRMAX + r) * SCAP;
    for (int i = e0 + t; i < e1; i += 256) {
        int v = sp[i];
        int dloc = (unsigned)v >> 16;
        int s = v & 0xFFFF;
        float w = dv[r0 + dloc] * dv[s];
        int pos = atomicAdd(&off[dloc], 1);
        cs[pos] = (int)((f2h16(w) << 16) | (unsigned)s);
    }
}

// ---------------- dual aggregation: one wave per node, 16-lane row groups ----------------
// cs payload {fp16 norm, src:16}; COLS elements per row (bf16 in h).
template <int COLS, typename OutT>
__global__ __launch_bounds__(256) void dualagg_kernel(
    const unsigned short* __restrict__ h1, const unsigned short* __restrict__ h2,
    const int* __restrict__ rp1, const int* __restrict__ cs1, const float* __restrict__ dv1,
    const int* __restrict__ rp2, const int* __restrict__ cs2, const float* __restrict__ dv2,
    const float* __restrict__ bias, OutT* __restrict__ o1, OutT* __restrict__ o2, int n) {
    constexpr int ACT = COLS / 8;   // active lanes per 16-lane group
    const unsigned short* h;
    const int *rp, *cs;
    const float* dv;
    OutT* out;
    if (blockIdx.y == 0) { h = h1; rp = rp1; cs = cs1; dv = dv1; out = o1; }
    else                 { h = h2; rp = rp2; cs = cs2; dv = dv2; out = o2; }
    int wid = blockIdx.x * 4 + (threadIdx.x >> 6);
    if (wid >= n) return;
    int lane = threadIdx.x & 63;
    int grp = lane >> 4;
    int li = lane & 15;
    bool act = li < ACT;
    float acc[8] = {0.f, 0.f, 0.f, 0.f, 0.f, 0.f, 0.f, 0.f};
    int e0 = rp[wid], e1 = rp[wid + 1];
    int e = e0 + grp;
    for (; e + 4 < e1; e += 8) {
        int va = cs[e], vb = cs[e + 4];
        float wa = h16f((unsigned)va >> 16); int sa = va & 0xFFFF;
        float wb = h16f((unsigned)vb >> 16); int sb = vb & 0xFFFF;
        if (act) {
            int4 ra = *(const int4*)(h + (size_t)sa * COLS + li * 8);
            int4 rb = *(const int4*)(h + (size_t)sb * COLS + li * 8);
            acc8(acc, wa, ra);
            acc8(acc, wb, rb);
        }
    }
    if (e < e1) {
        int va = cs[e];
        float wa = h16f((unsigned)va >> 16); int sa = va & 0xFFFF;
        if (act) {
            int4 ra = *(const int4*)(h + (size_t)sa * COLS + li * 8);
            acc8(acc, wa, ra);
        }
    }
#pragma unroll
    for (int j = 0; j < 8; ++j) {
        acc[j] += __shfl_xor(acc[j], 16);
        acc[j] += __shfl_xor(acc[j], 32);
    }
    if (grp == 0 && act) {
        float dn = dv[wid];
        float w = dn * dn;  // self-loop norm
        int4 rs = *(const int4*)(h + (size_t)wid * COLS + li * 8);
        acc8(acc, w, rs);
        float4 b0 = ((const float4*)bias)[li * 2];
        float4 b1 = ((const float4*)bias)[li * 2 + 1];
        acc[0] += b0.x; acc[1] += b0.y; acc[2] += b0.z; acc[3] += b0.w;
        acc[4] += b1.x; acc[5] += b1.y; acc[6] += b1.z; acc[7] += b1.w;
        if constexpr (sizeof(OutT) == 4) {
            float* op = (float*)out + (size_t)wid * COLS + li * 8;
            *(float4*)op = make_float4(acc[0], acc[1], acc[2], acc[3]);
            *(float4*)(op + 4) = make_float4(acc[4], acc[5], acc[6], acc[7]);
        } else {
            int4 o;
            o.x = (int)((unsigned)f2bf(acc[0]) | ((unsigned)f2bf(acc[1]) << 16));
            o.y = (int)((unsigned)f2bf(acc[2]) | ((unsigned)f2bf(acc[3]) << 16));
            o.z = (int)((unsigned)f2bf(acc[4]) | ((unsigned)f2bf(acc[5]) << 16));
            o.w = (int)((unsigned)f2bf(acc[6]) | ((unsigned)f2bf(acc[7]) << 16));
            *(int4*)((unsigned short*)out + (size_t)wid * COLS + li * 8) = o;
        }
    }
}

// ---------------- prep: Wm->Wt, Wi->hi/lo Wt1, zero gcount+ticks ----------------
__global__ __launch_bounds__(256) void prep_kernel(const float* __restrict__ Wm,
                                                   const float* __restrict__ Wi,
                                                   unsigned short* __restrict__ Wt,
                                                   unsigned short* __restrict__ Wt1,
                                                   int* __restrict__ zeros) {
    int b = blockIdx.x;
    int t = threadIdx.x;
    if (b < 128) {            // prepW: 2 layers x 16384
        int l = b >> 6;
        int o = (b & 63) * 256 + t;
        int kk = o & 31;
        int col = (o >> 5) & 127;
        int kc = o >> 12;
        int k = kc * 32 + kk;
        Wt[(size_t)l * 16384 + o] = f2bf(Wm[(size_t)l * 16384 + (size_t)k * 128 + col]);
    } else if (b < 256) {     // prepW1: 32768 hi/lo
        int o = (b - 128) * 256 + t;
        int kk = o & 31;
        int col = (o >> 5) & 63;
        int kc = (o >> 11) & 3;
        int hsel = (o >> 13) & 1;
        int s = (o >> 14) & 1;
        float w = Wi[(size_t)s * 8192 + (size_t)(kc * 32 + kk) * 64 + col];
        unsigned short hi = f2bf(w);
        Wt1[o] = hsel ? f2bf(w - bf2f(hi)) : hi;
    } else {                  // zero gcount (16) + tickets (3) region
        if (t < 32) zeros[t] = 0;
    }
}

// ---------------- Layer-1 MFMA GEMM, LDS-free (fp32-accurate hi/lo split) ----------------
__global__ __launch_bounds__(256) void gemm_l1_kernel(
    const float* __restrict__ x1a, const float* __restrict__ x1b, const float* __restrict__ x2a,
    const float* __restrict__ x2b, const unsigned short* __restrict__ Wt1,
    unsigned short* __restrict__ H1, unsigned short* __restrict__ H2, int nrows) {
    const float* X = (blockIdx.y == 0) ? x1a : (blockIdx.y == 1) ? x1b
                     : (blockIdx.y == 2) ? x2a : x2b;
    int slice = blockIdx.y & 1;
    unsigned short* Y = (blockIdx.y < 2) ? H1 : H2;
    int ocol = slice * 64;
    int tid = threadIdx.x;
    int row0 = blockIdx.x * 64;
    int wave = tid >> 6, lane = tid & 63;
    int m = lane & 15, quad = lane >> 4;
    int arow = row0 + wave * 16 + m;
    bool rv = arow < nrows;
    const float* xp = X + (size_t)arow * DFEAT;
    const unsigned short* Whp = Wt1 + (size_t)slice * 16384;
    const unsigned short* Wlp = Whp + 8192;
    f32x4 acc[4];
#pragma unroll
    for (int i = 0; i < 4; ++i) acc[i] = (f32x4){0.f, 0.f, 0.f, 0.f};
#pragma unroll
    for (int kc = 0; kc < 4; ++kc) {
        float4 f0 = make_float4(0.f, 0.f, 0.f, 0.f);
        float4 f1 = make_float4(0.f, 0.f, 0.f, 0.f);
        if (rv) {
            f0 = *(const float4*)(xp + kc * 32 + quad * 8);
            f1 = *(const float4*)(xp + kc * 32 + quad * 8 + 4);
        }
        float fs[8] = {f0.x, f0.y, f0.z, f0.w, f1.x, f1.y, f1.z, f1.w};
        bf16x8 ah, al;
#pragma unroll
        for (int j = 0; j < 8; ++j) {
            unsigned short hh = f2bf(fs[j]);
            ah[j] = (short)hh;
            al[j] = (short)f2bf(fs[j] - bf2f(hh));
        }
#pragma unroll
        for (int ct = 0; ct < 4; ++ct) {
            int wo = kc * 2048 + (ct * 16 + m) * 32 + quad * 8;
            bf16x8 bh = *(const bf16x8*)(Whp + wo);
            bf16x8 bl = *(const bf16x8*)(Wlp + wo);
            acc[ct] = __builtin_amdgcn_mfma_f32_16x16x32_bf16(ah, bh, acc[ct], 0, 0, 0);
            acc[ct] = __builtin_amdgcn_mfma_f32_16x16x32_bf16(al, bh, acc[ct], 0, 0, 0);
            acc[ct] = __builtin_amdgcn_mfma_f32_16x16x32_bf16(ah, bl, acc[ct], 0, 0, 0);
        }
    }
#pragma unroll
    for (int ct = 0; ct < 4; ++ct) {
#pragma unroll
        for (int i = 0; i < 4; ++i) {
            int gr = row0 + wave * 16 + quad * 4 + i;
            if (gr < nrows) Y[(size_t)gr * DFEAT + ocol + ct * 16 + m] = f2bf(acc[ct][i]);
        }
    }
}

// ---------------- MFMA fused GEMM (128->128): x = w1*relu(bn(A)) + w2*relu(bn(B)) ----------------
__global__ __launch_bounds__(256) void gemm_mfma_kernel(
    const unsigned short* __restrict__ Abf, const unsigned short* __restrict__ Bbf,
    const float* __restrict__ ss, const float* __restrict__ wout,
    const unsigned short* __restrict__ Wt, unsigned short* __restrict__ Y, int nrows) {
    __shared__ unsigned short Xs[64 * 128];
    int tid = threadIdx.x;
    int row0 = blockIdx.x * 64;
    int wave = tid >> 6, lane = tid & 63;
    int m = lane & 15, quad = lane >> 4;
    float w1 = wout[0], w2 = wout[1];
    for (int u = tid; u < 1024; u += 256) {
        int r = u >> 4;
        int col0 = (u & 15) * 8;
        int gr = row0 + r;
        int swz = (r & 7) << 3;
        if (gr < nrows) {
#pragma unroll
            for (int hh = 0; hh < 2; ++hh) {
                int c = col0 + hh * 4;
                float4 fa = bf4tof4(*(const ushort4*)(Abf + (size_t)gr * 128 + c));
                float4 fb = bf4tof4(*(const ushort4*)(Bbf + (size_t)gr * 128 + c));
                float4 sa = *(const float4*)(ss + c);
                float4 ha = *(const float4*)(ss + 128 + c);
                float4 sb = *(const float4*)(ss + 256 + c);
                float4 hb = *(const float4*)(ss + 384 + c);
                ushort4 o;
                o.x = f2bf(w1 * fmaxf(fmaf(fa.x, sa.x, ha.x), 0.f) +
                           w2 * fmaxf(fmaf(fb.x, sb.x, hb.x), 0.f));
                o.y = f2bf(w1 * fmaxf(fmaf(fa.y, sa.y, ha.y), 0.f) +
                           w2 * fmaxf(fmaf(fb.y, sb.y, hb.y), 0.f));
                o.z = f2bf(w1 * fmaxf(fmaf(fa.z, sa.z, ha.z), 0.f) +
                           w2 * fmaxf(fmaf(fb.z, sb.z, hb.z), 0.f));
                o.w = f2bf(w1 * fmaxf(fmaf(fa.w, sa.w, ha.w), 0.f) +
                           w2 * fmaxf(fmaf(fb.w, sb.w, hb.w), 0.f));
                *(ushort4*)&Xs[r * 128 + (c ^ swz)] = o;
            }
        } else {
            ushort4 z = {0, 0, 0, 0};
            *(ushort4*)&Xs[r * 128 + (col0 ^ swz)] = z;
            *(ushort4*)&Xs[r * 128 + ((col0 + 4) ^ swz)] = z;
        }
    }
    __syncthreads();
    f32x4 acc[8];
#pragma unroll
    for (int i = 0; i < 8; ++i) acc[i] = (f32x4){0.f, 0.f, 0.f, 0.f};
    int arow = wave * 16 + m;
#pragma unroll
    for (int kc = 0; kc < 4; ++kc) {
        int ac = (kc * 32 + quad * 8) ^ ((arow & 7) << 3);
        bf16x8 a = *(const bf16x8*)&Xs[arow * 128 + ac];
#pragma unroll
        for (int ct = 0; ct < 8; ++ct) {
            const unsigned short* bp = Wt + ((size_t)(kc * 128 + ct * 16 + m) * 32) + quad * 8;
            bf16x8 b = *(const bf16x8*)bp;
            acc[ct] = __builtin_amdgcn_mfma_f32_16x16x32_bf16(a, b, acc[ct], 0, 0, 0);
        }
    }
#pragma unroll
    for (int ct = 0; ct < 8; ++ct) {
#pragma unroll
        for (int i = 0; i < 4; ++i) {
            int gr = row0 + wave * 16 + quad * 4 + i;
            if (gr < nrows) Y[(size_t)gr * 128 + ct * 16 + m] = f2bf(acc[ct][i]);
        }
    }
}

// ---------------- VALU fused GEMM (final 128->40) ----------------
template <int CG, int RPT>
__global__ __launch_bounds__(256) void gemm_fused_kernel(
    const unsigned short* __restrict__ Abf, const unsigned short* __restrict__ Bbf,
    const float* __restrict__ ss, const float* __restrict__ wout, const float* __restrict__ W,
    unsigned short* __restrict__ Y, int nrows, int fout, int ostride) {
    __shared__ float Ws[32][CG * 4];
    __shared__ float Xs[64][33];
    int tid = threadIdx.x;
    int row0 = blockIdx.x * 64;
    int cg = tid % CG;
    int rg = tid / CG;
    float w1 = wout[0], w2 = wout[1];
    float4 acc[RPT];
#pragma unroll
    for (int i = 0; i < RPT; ++i) acc[i] = make_float4(0.f, 0.f, 0.f, 0.f);
    for (int kc = 0; kc < 4; ++kc) {
        for (int i = tid; i < 32 * CG; i += 256) {
            int r = i / CG, c = i % CG;
            float4 w;
            if ((c * 4 + 3) < fout) {
                w = *(const float4*)(W + (size_t)(kc * 32 + r) * fout + c * 4);
            } else {
                float t0 = (c * 4 + 0) < fout ? W[(size_t)(kc * 32 + r) * fout + c * 4 + 0] : 0.f;
                float t1 = (c * 4 + 1) < fout ? W[(size_t)(kc * 32 + r) * fout + c * 4 + 1] : 0.f;
                float t2 = (c * 4 + 2) < fout ? W[(size_t)(kc * 32 + r) * fout + c * 4 + 2] : 0.f;
                float t3 = (c * 4 + 3) < fout ? W[(size_t)(kc * 32 + r) * fout + c * 4 + 3] : 0.f;
                w = make_float4(t0, t1, t2, t3);
            }
            *(float4*)&Ws[r][c * 4] = w;
        }
        for (int i = tid; i < 64 * 8; i += 256) {
            int r = i / 8, c = i % 8;
            int gr = row0 + r;
            int col0 = kc * 32 + c * 4;
            float4 v = make_float4(0.f, 0.f, 0.f, 0.f);
            if (gr < nrows) {
                float4 a = bf4tof4(*(const ushort4*)(Abf + (size_t)gr * DFEAT + col0));
                float4 b = bf4tof4(*(const ushort4*)(Bbf + (size_t)gr * DFEAT + col0));
                float4 scA = *(const float4*)(ss + col0);
                float4 shA = *(const float4*)(ss + DFEAT + col0);
                float4 scB = *(const float4*)(ss + 2 * DFEAT + col0);
                float4 shB = *(const float4*)(ss + 3 * DFEAT + col0);
                v.x = w1 * fmaxf(fmaf(a.x, scA.x, shA.x), 0.f) +
                      w2 * fmaxf(fmaf(b.x, scB.x, shB.x), 0.f);
                v.y = w1 * fmaxf(fmaf(a.y, scA.y, shA.y), 0.f) +
                      w2 * fmaxf(fmaf(b.y, scB.y, shB.y), 0.f);
                v.z = w1 * fmaxf(fmaf(a.z, scA.z, shA.z), 0.f) +
                      w2 * fmaxf(fmaf(b.z, scB.z, shB.z), 0.f);
                v.w = w1 * fmaxf(fmaf(a.w, scA.w, shA.w), 0.f) +
                      w2 * fmaxf(fmaf(b.w, scB.w, shB.w), 0.f);
            }
            Xs[r][c * 4 + 0] = v.x;
            Xs[r][c * 4 + 1] = v.y;
            Xs[r][c * 4 + 2] = v.z;
            Xs[r][c * 4 + 3] = v.w;
        }
        __syncthreads();
#pragma unroll
        for (int k = 0; k < 32; ++k) {
            float4 w = *(float4*)&Ws[k][cg * 4];
#pragma unroll
            for (int i = 0; i < RPT; ++i) {
                float a = Xs[rg * RPT + i][k];
                acc[i].x = fmaf(a, w.x, acc[i].x);
                acc[i].y = fmaf(a, w.y, acc[i].y);
                acc[i].z = fmaf(a, w.z, acc[i].z);
                acc[i].w = fmaf(a, w.w, acc[i].w);
            }
        }
        __syncthreads();
    }
    if (cg * 4 < fout) {
#pragma unroll
        for (int i = 0; i < RPT; ++i) {
            int r = row0 + rg * RPT + i;
            if (r < nrows) {
                ushort4 o;
                o.x = f2bf(acc[i].x); o.y = f2bf(acc[i].y);
                o.z = f2bf(acc[i].z); o.w = f2bf(acc[i].w);
                *(ushort4*)(Y + (size_t)r * ostride + cg * 4) = o;
            }
        }
    }
}

// ---------------- fused BN stats + gate prep (atomic-ticket last block) ----------------
__global__ __launch_bounds__(256) void stats2g_kernel(
    const unsigned short* __restrict__ A, const unsigned short* __restrict__ B,
    float* __restrict__ stats, int nrows,
    const float* __restrict__ gamma, const float* __restrict__ beta,
    const float* __restrict__ gwA, const float* __restrict__ gbA,
    const float* __restrict__ gwB, const float* __restrict__ gbB,
    float* __restrict__ ss, float* __restrict__ wout, unsigned* __restrict__ tick) {
    __shared__ float red1[256];
    __shared__ float red2[256];
    int t = threadIdx.x;
    {
        int col = t & 127;
        int rg = t >> 7;
        const unsigned short* src = (blockIdx.y == 0) ? A : B;
        float* st = stats + (size_t)blockIdx.y * 256;
        int r0 = blockIdx.x * 128 + rg * 64;
        int r1 = min(r0 + 64, nrows);
        float s = 0.f, s2 = 0.f;
        for (int r = r0; r < r1; ++r) {
            float v = bf2f(src[(size_t)r * DFEAT + col]);
            s += v;
            s2 = fmaf(v, v, s2);
        }
        red1[t] = s;
        red2[t] = s2;
        __syncthreads();
        if (t < 128) {
            atomicAdd(&st[col], red1[t] + red1[t + 128]);
            atomicAdd(&st[DFEAT + col], red2[t] + red2[t + 128]);
        }
    }
    // ticket: last block does gate prep
    __threadfence();
    __shared__ int amlast;
    __syncthreads();
    if (t == 0) {
        unsigned v = atomicAdd(tick, 1u);
        amlast = (v == gridDim.x * gridDim.y - 1) ? 1 : 0;
    }
    __syncthreads();
    if (!amlast) return;
    __shared__ float red[128];
    __shared__ float dotA_s;
    float invN = 1.f / (float)nrows;
    float scA = 0.f, shA = 0.f, scB = 0.f, shB = 0.f;
    if (t < 128) {
        // stats were written by ATOMICS -> re-read via atomic for coherence
        float sA = atomicAdd(&stats[t], 0.f);
        float s2A = atomicAdd(&stats[DFEAT + t], 0.f);
        float sB = atomicAdd(&stats[256 + t], 0.f);
        float s2B = atomicAdd(&stats[256 + DFEAT + t], 0.f);
        float meanA = sA * invN;
        float varA = s2A * invN - meanA * meanA;
        scA = gamma[t] * rsqrtf(varA + 1e-5f);
        shA = beta[t] - meanA * scA;
        ss[t] = scA;
        ss[DFEAT + t] = shA;
        float meanB = sB * invN;
        float varB = s2B * invN - meanB * meanB;
        scB = gamma[t] * rsqrtf(varB + 1e-5f);
        shB = beta[t] - meanB * scB;
        ss[2 * DFEAT + t] = scB;
        ss[3 * DFEAT + t] = shB;
        stats[t] = 0.f;
        stats[DFEAT + t] = 0.f;
        stats[256 + t] = 0.f;
        stats[256 + DFEAT + t] = 0.f;
        float av = fmaxf(fmaf(bf2f(A[(size_t)(nrows - 1) * DFEAT + t]), scA, shA), 0.f);
        red[t] = av * gwA[t];
    }
    __syncthreads();
    for (int s = 64; s > 0; s >>= 1) {
        if (t < s) red[t] += red[t + s];
        __syncthreads();
    }
    if (t == 0) dotA_s = red[0];
    __syncthreads();
    if (t < 128) {
        float bv = fmaxf(fmaf(bf2f(B[(size_t)(nrows - 1) * DFEAT + t]), scB, shB), 0.f);
        red[t] = bv * gwB[t];
    }
    __syncthreads();
    for (int s = 64; s > 0; s >>= 1) {
        if (t < s) red[t] += red[t + s];
        __syncthreads();
    }
    if (t == 0) {
        float s1 = 1.f / (1.f + expf(-(dotA_s + gbA[0])));
        float s2 = 1.f / (1.f + expf(-(red[0] + gbB[0])));
        float tt = s1 + s2;
        wout[0] = s1 / tt;
        wout[1] = s2 / tt;
    }
}

__global__ __launch_bounds__(64) void gate_final_kernel(
    const float* __restrict__ p1, const float* __restrict__ p2,
    const float* __restrict__ w1v, const float* __restrict__ b1,
    const float* __restrict__ w2v, const float* __restrict__ b2,
    float* __restrict__ wout, int nrows, int nclass) {
    __shared__ float red[64];
    __shared__ float dot1_s;
    int t = threadIdx.x;
    float v = (t < nclass) ? p1[(size_t)(nrows - 1) * nclass + t] * w1v[t] : 0.f;
    red[t] = v;
    __syncthreads();
    for (int s = 32; s > 0; s >>= 1) {
        if (t < s) red[t] += red[t + s];
        __syncthreads();
    }
    if (t == 0) dot1_s = red[0];
    __syncthreads();
    v = (t < nclass) ? p2[(size_t)(nrows - 1) * nclass + t] * w2v[t] : 0.f;
    red[t] = v;
    __syncthreads();
    for (int s = 32; s > 0; s >>= 1) {
        if (t < s) red[t] += red[t + s];
        __syncthreads();
    }
    if (t == 0) {
        float s1 = 1.f / (1.f + expf(-(dot1_s + b1[0])));
        float s2 = 1.f / (1.f + expf(-(red[0] + b2[0])));
        float tt = s1 + s2;
        wout[0] = s1 / tt;
        wout[1] = s2 / tt;
    }
}

__global__ __launch_bounds__(256) void mix_kernel(const float* __restrict__ p1,
                                                  const float* __restrict__ p2,
                                                  const float* __restrict__ wout,
                                                  float* __restrict__ o, int n4) {
    int idx = blockIdx.x * blockDim.x + threadIdx.x;
    if (idx >= n4) return;
    float w1 = wout[0], w2 = wout[1];
    float4 a = *(const float4*)(p1 + (size_t)idx * 4);
    float4 b = *(const float4*)(p2 + (size_t)idx * 4);
    float4 r = make_float4(w1 * a.x + w2 * b.x, w1 * a.y + w2 * b.y, w1 * a.z + w2 * b.z,
                           w1 * a.w + w2 * b.w);
    *(float4*)(o + (size_t)idx * 4) = r;
}

extern "C" void kernel_launch(void* const* d_in, const int* in_sizes, int n_in, void* d_out,
                              int out_size, void* d_ws, size_t ws_size, hipStream_t stream) {
    (void)n_in; (void)out_size; (void)ws_size;
    const int N = in_sizes[0] / DFEAT;        // 50000
    const int E = in_sizes[4] / 2;            // 800000
    const int NC = in_sizes[15];              // 40

    const float* x1a = (const float*)d_in[0];
    const float* x1b = (const float*)d_in[1];
    const float* x2a = (const float*)d_in[2];
    const float* x2b = (const float*)d_in[3];
    const int* ei1 = (const int*)d_in[4];
    const int* ei2 = (const int*)d_in[5];
    const float* Wi = (const float*)d_in[6];
    const float* bi = (const float*)d_in[7];
    const float* gi = (const float*)d_in[8];
    const float* bei = (const float*)d_in[9];
    const float* Wm = (const float*)d_in[10];
    const float* bm = (const float*)d_in[11];
    const float* gm = (const float*)d_in[12];
    const float* bem = (const float*)d_in[13];
    const float* Wf = (const float*)d_in[14];
    const float* bf = (const float*)d_in[15];
    const float* fc1w1_W = (const float*)d_in[16];
    const float* fc1w1_b = (const float*)d_in[17];
    const float* fc1w2_W = (const float*)d_in[18];
    const float* fc1w2_b = (const float*)d_in[19];
    const float* aws_w1_W = (const float*)d_in[20];
    const float* aws_w1_b = (const float*)d_in[21];
    const float* aws_w2_W = (const float*)d_in[22];
    const float* aws_w2_b = (const float*)d_in[23];
    const float* fcw1_W = (const float*)d_in[24];
    const float* fcw1_b = (const float*)d_in[25];
    const float* fcw2_W = (const float*)d_in[26];
    const float* fcw2_b = (const float*)d_in[27];

    char* ws = (char*)d_ws;
    size_t off = 0;
    auto alloc = [&](size_t bytes) -> char* {
        char* p = ws + off;
        off += (bytes + 255) & ~(size_t)255;
        return p;
    };
    unsigned short* A = (unsigned short*)alloc((size_t)N * DFEAT * 2);
    unsigned short* B = (unsigned short*)alloc((size_t)N * DFEAT * 2);
    unsigned short* H1 = (unsigned short*)alloc((size_t)N * DFEAT * 2);
    unsigned short* H2 = (unsigned short*)alloc((size_t)N * DFEAT * 2);
    int* rp1 = (int*)alloc((size_t)(N + 1) * 4);
    int* rp2 = (int*)alloc((size_t)(N + 1) * 4);
    int* cnt1 = (int*)alloc((size_t)N * 4);
    int* cnt2 = (int*)alloc((size_t)N * 4);
    float* dv1 = (float*)alloc((size_t)N * 4);
    float* dv2 = (float*)alloc((size_t)N * 4);
    int* cs1 = (int*)alloc((size_t)E * 4);
    int* cs2 = (int*)alloc((size_t)E * 4);
    int* stg = (int*)alloc((size_t)2 * NRMAX * SCAP * 4);             // 10.2 MB
    int* baseB = (int*)alloc(((size_t)2 * NRMAX * SUBS << RSH) * 4);  // 16.8 MB
    int* gcount = (int*)alloc(32 * 4);        // 16 counts + 3 tickets (+pad)
    unsigned* tick = (unsigned*)(gcount + 24);
    unsigned short* Wt = (unsigned short*)alloc((size_t)2 * 16384 * 2);
    unsigned short* Wt1 = (unsigned short*)alloc((size_t)32768 * 2);  // 64 KB
    float* stats = (float*)alloc(2048);
    float* ssbuf = (float*)alloc(2048);
    float* wout = (float*)alloc(256);
    int nb = (N + 255) / 256;                 // 196 (scanB/writerp blocking, <=256)
    int* bsums = (int*)alloc((size_t)2 * nb * 4);

    const int* src1 = ei1;
    const int* dst1 = ei1 + E;
    const int* src2 = ei2;
    const int* dst2 = ei2 + E;

    int nr = (N + RSZ - 1) >> RSH;            // 7
    int gemmbl = (N + 63) / 64;
    dim3 pagrid((E + EPA - 1) / EPA, 2);      // 391 x 2
    dim3 rsgrid(nr * SUBS, 2);                // 112 x 2
    dim3 nodegrid(nb, 2);
    dim3 agggrid((N + 3) / 4, 2);
    dim3 statgrid((N + 127) / 128, 2);
    dim3 l1grid(gemmbl, 4);

    // ---- prep + CSR build (two-level counting sort, LDS atomics only) ----
    prep_kernel<<<257, 256, 0, stream>>>(Wm, Wi, Wt, Wt1, gcount);
    partA_kernel<<<pagrid, 256, 0, stream>>>(src1, dst1, src2, dst2, stg, gcount, E, nr);
    histB_kernel<<<rsgrid, 256, 0, stream>>>(stg, gcount, baseB, nr);
    scanB_kernel<<<nodegrid, 256, 0, stream>>>(baseB, cnt1, cnt2, bsums, N, nb);
    scansums_kernel<<<1, 256, 0, stream>>>(bsums, nb, rp1, rp2, N, E, stats);
    writerp_kernel<<<nodegrid, 256, 0, stream>>>(cnt1, cnt2, bsums, rp1, rp2, dv1, dv2, N, nb);
    fillC_kernel<<<rsgrid, 256, 0, stream>>>(stg, gcount, baseB, rp1, rp2, dv1, dv2,
                                             cs1, cs2, N, nr);

    // ---- Layer 1 ----
    gemm_l1_kernel<<<l1grid, 256, 0, stream>>>(x1a, x1b, x2a, x2b, Wt1, H1, H2, N);
    dualagg_kernel<128, unsigned short><<<agggrid, 256, 0, stream>>>(
        H1, H2, rp1, cs1, dv1, rp2, cs2, dv2, bi, A, B, N);
    stats2g_kernel<<<statgrid, 256, 0, stream>>>(A, B, stats, N, gi, bei, fc1w1_W, fc1w1_b,
                                                 fc1w2_W, fc1w2_b, ssbuf, wout, tick);

    // ---- Middle layer 0 ----
    gemm_mfma_kernel<<<gemmbl, 256, 0, stream>>>(A, B, ssbuf, wout, Wt, H1, N);
    dualagg_kernel<128, unsigned short><<<agggrid, 256, 0, stream>>>(
        H1, H1, rp1, cs1, dv1, rp2, cs2, dv2, bm, A, B, N);
    stats2g_kernel<<<statgrid, 256, 0, stream>>>(A, B, stats, N, gm, bem, aws_w1_W, aws_w1_b,
                                                 aws_w2_W, aws_w2_b, ssbuf, wout, tick + 1);

    // ---- Middle layer 1 ----
    gemm_mfma_kernel<<<gemmbl, 256, 0, stream>>>(A, B, ssbuf, wout, Wt + 16384, H1, N);
    dualagg_kernel<128, unsigned short><<<agggrid, 256, 0, stream>>>(
        H1, H1, rp1, cs1, dv1, rp2, cs2, dv2, bm + 128, A, B, N);
    stats2g_kernel<<<statgrid, 256, 0, stream>>>(A, B, stats, N, gm + 128, bem + 128,
                                                 aws_w1_W + 128, aws_w1_b + 1, aws_w2_W + 128,
                                                 aws_w2_b + 1, ssbuf, wout, tick + 2);

    // ---- Final layer ----
    float* out0 = (float*)d_out;
    float* p1 = out0 + (size_t)N * NC;
    float* p2 = out0 + (size_t)2 * N * NC;
    gemm_fused_kernel<16, 4><<<gemmbl, 256, 0, stream>>>(A, B, ssbuf, wout, Wf, H2, N, NC, NC);
    dualagg_kernel<40, float><<<agggrid, 256, 0, stream>>>(H2, H2, rp1, cs1, dv1, rp2, cs2, dv2,
                                                           bf, p1, p2, N);
    gate_final_kernel<<<1, 64, 0, stream>>>(p1, p2, fcw1_W, fcw1_b, fcw2_W, fcw2_b, wout, N, NC);
    mix_kernel<<<(N * NC / 4 + 255) / 256, 256, 0, stream>>>(p1, p2, wout, out0, N * NC / 4);
}

// Round 10
// 626.285 us; speedup vs baseline: 1.3756x; 1.2302x over previous
//
#include <hip/hip_runtime.h>
#include <hip/hip_fp16.h>

// CLAGCN forward on MI355X.
// R1-R13: counting-sort CSR build, MFMA GEMMs, LDS-free l1, 16-lane dualagg. 669us.
// R14 (FAILED): dualagg col-split issue-bound; serial scansums. 862us.
// R15 (PARTIAL FAIL): dualagg/scansums fixed, but ticket-fused stats2g = 70us x3:
//     __threadfence() (device-scope release) forces an L2 writeback PER BLOCK
//     (782 blocks) on non-coherent-XCD gfx950. Fusion across a device-wide
//     reduction loses; kernel boundary gives coherence for free.
// R16: un-fuse stats+gate (R13 two-kernel form, no fence/ticket); stats2
//     vectorized int4 loads (was 64 scalar ushort loads/thread) + shfl/LDS
//     reduce. Keep prep fusion, scanB fold, parallel scansums.

#define DFEAT 128

typedef __attribute__((ext_vector_type(8))) short bf16x8;
typedef __attribute__((ext_vector_type(4))) float f32x4;

__device__ __forceinline__ unsigned short f2bf(float f) {
    unsigned u = __float_as_uint(f);
    u += 0x7fffu + ((u >> 16) & 1u);
    return (unsigned short)(u >> 16);
}
__device__ __forceinline__ float bf2f(unsigned short u) {
    return __uint_as_float((unsigned)u << 16);
}
__device__ __forceinline__ unsigned f2h16(float f) {
    return (unsigned)__half_as_ushort(__float2half(f));
}
__device__ __forceinline__ float h16f(unsigned u) {
    return __half2float(__ushort_as_half((unsigned short)u));
}
__device__ __forceinline__ float4 bf4tof4(ushort4 u) {
    return make_float4(__uint_as_float((unsigned)u.x << 16),
                       __uint_as_float((unsigned)u.y << 16),
                       __uint_as_float((unsigned)u.z << 16),
                       __uint_as_float((unsigned)u.w << 16));
}
// accumulate 8 bf16 (packed in int4) * w into acc[8]
__device__ __forceinline__ void acc8(float* acc, float w, int4 r) {
    int vs[4] = {r.x, r.y, r.z, r.w};
#pragma unroll
    for (int q = 0; q < 4; ++q) {
        float lo = __uint_as_float((unsigned)vs[q] << 16);
        float hi = __uint_as_float((unsigned)vs[q] & 0xffff0000u);
        acc[q * 2] = fmaf(w, lo, acc[q * 2]);
        acc[q * 2 + 1] = fmaf(w, hi, acc[q * 2 + 1]);
    }
}

// ---------------- two-level counting-sort CSR build ----------------
constexpr int RSH = 13;        // range shift -> 8192 nodes per range
constexpr int RSZ = 8192;
constexpr int NRMAX = 8;       // max ranges (N <= 65536)
constexpr int EPA = 2048;      // edges per partition block
constexpr int SUBS = 16;       // sub-slices per range for hist/fill
constexpr int SCAP = 160000;   // stream capacity per (graph, range)

__global__ __launch_bounds__(256) void partA_kernel(
    const int* __restrict__ src1, const int* __restrict__ dst1,
    const int* __restrict__ src2, const int* __restrict__ dst2,
    int* __restrict__ stg, int* __restrict__ gcount, int E, int nr) {
    int g = blockIdx.y;
    const int* src = g ? src2 : src1;
    const int* dst = g ? dst2 : dst1;
    __shared__ int buf[EPA];
    __shared__ int buf2[EPA];
    __shared__ int cnt8[NRMAX + 1], pre8[NRMAX + 1], base8[NRMAX];
    int t = threadIdx.x;
    if (t < NRMAX) cnt8[t] = 0;
    __syncthreads();
    int e0 = blockIdx.x * EPA;
    int e1 = min(e0 + EPA, E);
    int ec = e1 - e0;
    for (int i = e0 + t; i < e1; i += 256) {
        int d = dst[i];
        int s = src[i];
        buf[i - e0] = (d << 16) | s;
        atomicAdd(&cnt8[d >> RSH], 1);
    }
    __syncthreads();
    if (t == 0) {
        int run = 0;
        for (int r = 0; r < nr; ++r) { pre8[r] = run; run += cnt8[r]; }
        pre8[nr] = run;
    }
    __syncthreads();
    if (t < nr) {
        base8[t] = atomicAdd(&gcount[g * NRMAX + t], cnt8[t]);
        cnt8[t] = 0;
    }
    __syncthreads();
    for (int j = t; j < ec; j += 256) {
        int v = buf[j];
        int d = (unsigned)v >> 16;
        int r = d >> RSH;
        int p = pre8[r] + atomicAdd(&cnt8[r], 1);
        buf2[p] = ((d & (RSZ - 1)) << 16) | (v & 0xFFFF);
    }
    __syncthreads();
    for (int j = t; j < ec; j += 256) {
        int r = 0;
        while (j >= pre8[r + 1]) ++r;
        int gpos = base8[r] + (j - pre8[r]);
        if (gpos < SCAP) stg[((size_t)g * NRMAX + r) * SCAP + gpos] = buf2[j];
    }
}

__global__ __launch_bounds__(256) void histB_kernel(
    const int* __restrict__ stg, const int* __restrict__ gcount,
    int* __restrict__ baseB, int nr) {
    int g = blockIdx.y;
    int r = blockIdx.x / SUBS;
    int sub = blockIdx.x % SUBS;
    __shared__ int hist[RSZ];
    int t = threadIdx.x;
    for (int i = t; i < RSZ; i += 256) hist[i] = 0;
    __syncthreads();
    int len = min(gcount[g * NRMAX + r], SCAP);
    int seg = (len + SUBS - 1) / SUBS;
    int e0 = sub * seg, e1 = min(e0 + seg, len);
    const int* sp = stg + ((size_t)g * NRMAX + r) * SCAP;
    for (int i = e0 + t; i < e1; i += 256) atomicAdd(&hist[(unsigned)sp[i] >> 16], 1);
    __syncthreads();
    int* bp = baseB + (((size_t)(g * NRMAX + r) * SUBS + sub) << RSH);
    for (int i = t; i < RSZ; i += 256) bp[i] = hist[i];
}

// scanB: per-node exclusive prefix over subs -> cnt, PLUS block total -> bsums
__global__ __launch_bounds__(256) void scanB_kernel(
    int* __restrict__ baseB, int* __restrict__ cnt1, int* __restrict__ cnt2,
    int* __restrict__ bsums, int n, int nb) {
    int node = blockIdx.x * 256 + threadIdx.x;
    int g = blockIdx.y;
    int t = threadIdx.x;
    int run = 0;
    if (node < n) {
        int r = node >> RSH, dloc = node & (RSZ - 1);
        int* p = baseB + (((size_t)(g * NRMAX + r) * SUBS) << RSH) + dloc;
#pragma unroll
        for (int s = 0; s < SUBS; ++s) {
            int v = p[(size_t)s << RSH];
            p[(size_t)s << RSH] = run;
            run += v;
        }
        (g ? cnt2 : cnt1)[node] = run;
    }
    __shared__ int red[256];
    red[t] = run;
    __syncthreads();
    for (int o = 128; o > 0; o >>= 1) {
        if (t < o) red[t] += red[t + o];
        __syncthreads();
    }
    if (t == 0) bsums[(size_t)g * nb + blockIdx.x] = red[0];
}

// parallel exclusive scan of bsums (nb <= 256) for both graphs; zero stats.
__global__ __launch_bounds__(256) void scansums_kernel(
    int* __restrict__ bs, int nb, int* __restrict__ rp1, int* __restrict__ rp2,
    int n, int E, float* __restrict__ stats) {
    __shared__ int red[256];
    int t = threadIdx.x;
    for (int g = 0; g < 2; ++g) {
        int v = (t < nb) ? bs[(size_t)g * nb + t] : 0;
        red[t] = v;
        __syncthreads();
        for (int o = 1; o < 256; o <<= 1) {
            int x = (t >= o) ? red[t - o] : 0;
            __syncthreads();
            red[t] += x;
            __syncthreads();
        }
        if (t < nb) bs[(size_t)g * nb + t] = red[t] - v;  // exclusive
        __syncthreads();
    }
    if (t < 2) (t ? rp2 : rp1)[n] = E;
    for (int i = t; i < 512; i += 256) stats[i] = 0.f;
}

// writerp: 256 nodes/block (matches scanB blocking), in-block scan
__global__ __launch_bounds__(256) void writerp_kernel(
    const int* __restrict__ c1, const int* __restrict__ c2, const int* __restrict__ bs,
    int* __restrict__ rp1, int* __restrict__ rp2,
    float* __restrict__ dv1, float* __restrict__ dv2, int n, int nb) {
    const int* c = blockIdx.y ? c2 : c1;
    int* rp = blockIdx.y ? rp2 : rp1;
    float* dv = blockIdx.y ? dv2 : dv1;
    int t = threadIdx.x;
    int node = blockIdx.x * 256 + t;
    int v = (node < n) ? c[node] : 0;
    __shared__ int red[256];
    red[t] = v;
    __syncthreads();
    for (int o = 1; o < 256; o <<= 1) {
        int x = (t >= o) ? red[t - o] : 0;
        __syncthreads();
        red[t] += x;
        __syncthreads();
    }
    if (node < n) {
        int run = bs[(size_t)blockIdx.y * nb + blockIdx.x] + red[t] - v;
        rp[node] = run;
        dv[node] = rsqrtf((float)(v + 1));  // +1 self-loop
    }
}

__global__ __launch_bounds__(256) void fillC_kernel(
    const int* __restrict__ stg, const int* __restrict__ gcount,
    const int* __restrict__ baseB,
    const int* __restrict__ rp1, const int* __restrict__ rp2,
    const float* __restrict__ dv1, const float* __restrict__ dv2,
    int* __restrict__ cs1, int* __restrict__ cs2, int n, int nr) {
    int g = blockIdx.y;
    int r = blockIdx.x / SUBS;
    int sub = blockIdx.x % SUBS;
    const int* rp = g ? rp2 : rp1;
    const float* dv = g ? dv2 : dv1;
    int* cs = g ? cs2 : cs1;
    __shared__ int off[RSZ];
    int t = threadIdx.x;
    int r0 = r << RSH;
    int rn = min(RSZ, n - r0);
    if (rn <= 0) return;
    const int* bp = baseB + (((size_t)(g * NRMAX + r) * SUBS + sub) << RSH);
    for (int i = t; i < rn; i += 256) off[i] = bp[i] + rp[r0 + i];
    __syncthreads();
    int len = min(gcount[g * NRMAX + r], SCAP);
    int seg = (len + SUBS - 1) / SUBS;
    int e0 = sub * seg, e1 = min(e0 + seg, len);
    const int* sp = stg + ((size_t)g * NRMAX + r) * SCAP;
    for (int i = e0 + t; i < e1; i += 256) {
        int v = sp[i];
        int dloc = (unsigned)v >> 16;
        int s = v & 0xFFFF;
        float w = dv[r0 + dloc] * dv[s];
        int pos = atomicAdd(&off[dloc], 1);
        cs[pos] = (int)((f2h16(w) << 16) | (unsigned)s);
    }
}

// ---------------- dual aggregation: one wave per node, 16-lane row groups ----------------
template <int COLS, typename OutT>
__global__ __launch_bounds__(256) void dualagg_kernel(
    const unsigned short* __restrict__ h1, const unsigned short* __restrict__ h2,
    const int* __restrict__ rp1, const int* __restrict__ cs1, const float* __restrict__ dv1,
    const int* __restrict__ rp2, const int* __restrict__ cs2, const float* __restrict__ dv2,
    const float* __restrict__ bias, OutT* __restrict__ o1, OutT* __restrict__ o2, int n) {
    constexpr int ACT = COLS / 8;   // active lanes per 16-lane group
    const unsigned short* h;
    const int *rp, *cs;
    const float* dv;
    OutT* out;
    if (blockIdx.y == 0) { h = h1; rp = rp1; cs = cs1; dv = dv1; out = o1; }
    else                 { h = h2; rp = rp2; cs = cs2; dv = dv2; out = o2; }
    int wid = blockIdx.x * 4 + (threadIdx.x >> 6);
    if (wid >= n) return;
    int lane = threadIdx.x & 63;
    int grp = lane >> 4;
    int li = lane & 15;
    bool act = li < ACT;
    float acc[8] = {0.f, 0.f, 0.f, 0.f, 0.f, 0.f, 0.f, 0.f};
    int e0 = rp[wid], e1 = rp[wid + 1];
    int e = e0 + grp;
    for (; e + 4 < e1; e += 8) {
        int va = cs[e], vb = cs[e + 4];
        float wa = h16f((unsigned)va >> 16); int sa = va & 0xFFFF;
        float wb = h16f((unsigned)vb >> 16); int sb = vb & 0xFFFF;
        if (act) {
            int4 ra = *(const int4*)(h + (size_t)sa * COLS + li * 8);
            int4 rb = *(const int4*)(h + (size_t)sb * COLS + li * 8);
            acc8(acc, wa, ra);
            acc8(acc, wb, rb);
        }
    }
    if (e < e1) {
        int va = cs[e];
        float wa = h16f((unsigned)va >> 16); int sa = va & 0xFFFF;
        if (act) {
            int4 ra = *(const int4*)(h + (size_t)sa * COLS + li * 8);
            acc8(acc, wa, ra);
        }
    }
#pragma unroll
    for (int j = 0; j < 8; ++j) {
        acc[j] += __shfl_xor(acc[j], 16);
        acc[j] += __shfl_xor(acc[j], 32);
    }
    if (grp == 0 && act) {
        float dn = dv[wid];
        float w = dn * dn;  // self-loop norm
        int4 rs = *(const int4*)(h + (size_t)wid * COLS + li * 8);
        acc8(acc, w, rs);
        float4 b0 = ((const float4*)bias)[li * 2];
        float4 b1 = ((const float4*)bias)[li * 2 + 1];
        acc[0] += b0.x; acc[1] += b0.y; acc[2] += b0.z; acc[3] += b0.w;
        acc[4] += b1.x; acc[5] += b1.y; acc[6] += b1.z; acc[7] += b1.w;
        if constexpr (sizeof(OutT) == 4) {
            float* op = (float*)out + (size_t)wid * COLS + li * 8;
            *(float4*)op = make_float4(acc[0], acc[1], acc[2], acc[3]);
            *(float4*)(op + 4) = make_float4(acc[4], acc[5], acc[6], acc[7]);
        } else {
            int4 o;
            o.x = (int)((unsigned)f2bf(acc[0]) | ((unsigned)f2bf(acc[1]) << 16));
            o.y = (int)((unsigned)f2bf(acc[2]) | ((unsigned)f2bf(acc[3]) << 16));
            o.z = (int)((unsigned)f2bf(acc[4]) | ((unsigned)f2bf(acc[5]) << 16));
            o.w = (int)((unsigned)f2bf(acc[6]) | ((unsigned)f2bf(acc[7]) << 16));
            *(int4*)((unsigned short*)out + (size_t)wid * COLS + li * 8) = o;
        }
    }
}

// ---------------- prep: Wm->Wt, Wi->hi/lo Wt1, zero gcount ----------------
__global__ __launch_bounds__(256) void prep_kernel(const float* __restrict__ Wm,
                                                   const float* __restrict__ Wi,
                                                   unsigned short* __restrict__ Wt,
                                                   unsigned short* __restrict__ Wt1,
                                                   int* __restrict__ zeros) {
    int b = blockIdx.x;
    int t = threadIdx.x;
    if (b < 128) {            // prepW: 2 layers x 16384
        int l = b >> 6;
        int o = (b & 63) * 256 + t;
        int kk = o & 31;
        int col = (o >> 5) & 127;
        int kc = o >> 12;
        int k = kc * 32 + kk;
        Wt[(size_t)l * 16384 + o] = f2bf(Wm[(size_t)l * 16384 + (size_t)k * 128 + col]);
    } else if (b < 256) {     // prepW1: 32768 hi/lo
        int o = (b - 128) * 256 + t;
        int kk = o & 31;
        int col = (o >> 5) & 63;
        int kc = (o >> 11) & 3;
        int hsel = (o >> 13) & 1;
        int s = (o >> 14) & 1;
        float w = Wi[(size_t)s * 8192 + (size_t)(kc * 32 + kk) * 64 + col];
        unsigned short hi = f2bf(w);
        Wt1[o] = hsel ? f2bf(w - bf2f(hi)) : hi;
    } else {                  // zero gcount region
        if (t < 32) zeros[t] = 0;
    }
}

// ---------------- Layer-1 MFMA GEMM, LDS-free (fp32-accurate hi/lo split) ----------------
__global__ __launch_bounds__(256) void gemm_l1_kernel(
    const float* __restrict__ x1a, const float* __restrict__ x1b, const float* __restrict__ x2a,
    const float* __restrict__ x2b, const unsigned short* __restrict__ Wt1,
    unsigned short* __restrict__ H1, unsigned short* __restrict__ H2, int nrows) {
    const float* X = (blockIdx.y == 0) ? x1a : (blockIdx.y == 1) ? x1b
                     : (blockIdx.y == 2) ? x2a : x2b;
    int slice = blockIdx.y & 1;
    unsigned short* Y = (blockIdx.y < 2) ? H1 : H2;
    int ocol = slice * 64;
    int tid = threadIdx.x;
    int row0 = blockIdx.x * 64;
    int wave = tid >> 6, lane = tid & 63;
    int m = lane & 15, quad = lane >> 4;
    int arow = row0 + wave * 16 + m;
    bool rv = arow < nrows;
    const float* xp = X + (size_t)arow * DFEAT;
    const unsigned short* Whp = Wt1 + (size_t)slice * 16384;
    const unsigned short* Wlp = Whp + 8192;
    f32x4 acc[4];
#pragma unroll
    for (int i = 0; i < 4; ++i) acc[i] = (f32x4){0.f, 0.f, 0.f, 0.f};
#pragma unroll
    for (int kc = 0; kc < 4; ++kc) {
        float4 f0 = make_float4(0.f, 0.f, 0.f, 0.f);
        float4 f1 = make_float4(0.f, 0.f, 0.f, 0.f);
        if (rv) {
            f0 = *(const float4*)(xp + kc * 32 + quad * 8);
            f1 = *(const float4*)(xp + kc * 32 + quad * 8 + 4);
        }
        float fs[8] = {f0.x, f0.y, f0.z, f0.w, f1.x, f1.y, f1.z, f1.w};
        bf16x8 ah, al;
#pragma unroll
        for (int j = 0; j < 8; ++j) {
            unsigned short hh = f2bf(fs[j]);
            ah[j] = (short)hh;
            al[j] = (short)f2bf(fs[j] - bf2f(hh));
        }
#pragma unroll
        for (int ct = 0; ct < 4; ++ct) {
            int wo = kc * 2048 + (ct * 16 + m) * 32 + quad * 8;
            bf16x8 bh = *(const bf16x8*)(Whp + wo);
            bf16x8 bl = *(const bf16x8*)(Wlp + wo);
            acc[ct] = __builtin_amdgcn_mfma_f32_16x16x32_bf16(ah, bh, acc[ct], 0, 0, 0);
            acc[ct] = __builtin_amdgcn_mfma_f32_16x16x32_bf16(al, bh, acc[ct], 0, 0, 0);
            acc[ct] = __builtin_amdgcn_mfma_f32_16x16x32_bf16(ah, bl, acc[ct], 0, 0, 0);
        }
    }
#pragma unroll
    for (int ct = 0; ct < 4; ++ct) {
#pragma unroll
        for (int i = 0; i < 4; ++i) {
            int gr = row0 + wave * 16 + quad * 4 + i;
            if (gr < nrows) Y[(size_t)gr * DFEAT + ocol + ct * 16 + m] = f2bf(acc[ct][i]);
        }
    }
}

// ---------------- MFMA fused GEMM (128->128): x = w1*relu(bn(A)) + w2*relu(bn(B)) ----------------
__global__ __launch_bounds__(256) void gemm_mfma_kernel(
    const unsigned short* __restrict__ Abf, const unsigned short* __restrict__ Bbf,
    const float* __restrict__ ss, const float* __restrict__ wout,
    const unsigned short* __restrict__ Wt, unsigned short* __restrict__ Y, int nrows) {
    __shared__ unsigned short Xs[64 * 128];
    int tid = threadIdx.x;
    int row0 = blockIdx.x * 64;
    int wave = tid >> 6, lane = tid & 63;
    int m = lane & 15, quad = lane >> 4;
    float w1 = wout[0], w2 = wout[1];
    for (int u = tid; u < 1024; u += 256) {
        int r = u >> 4;
        int col0 = (u & 15) * 8;
        int gr = row0 + r;
        int swz = (r & 7) << 3;
        if (gr < nrows) {
#pragma unroll
            for (int hh = 0; hh < 2; ++hh) {
                int c = col0 + hh * 4;
                float4 fa = bf4tof4(*(const ushort4*)(Abf + (size_t)gr * 128 + c));
                float4 fb = bf4tof4(*(const ushort4*)(Bbf + (size_t)gr * 128 + c));
                float4 sa = *(const float4*)(ss + c);
                float4 ha = *(const float4*)(ss + 128 + c);
                float4 sb = *(const float4*)(ss + 256 + c);
                float4 hb = *(const float4*)(ss + 384 + c);
                ushort4 o;
                o.x = f2bf(w1 * fmaxf(fmaf(fa.x, sa.x, ha.x), 0.f) +
                           w2 * fmaxf(fmaf(fb.x, sb.x, hb.x), 0.f));
                o.y = f2bf(w1 * fmaxf(fmaf(fa.y, sa.y, ha.y), 0.f) +
                           w2 * fmaxf(fmaf(fb.y, sb.y, hb.y), 0.f));
                o.z = f2bf(w1 * fmaxf(fmaf(fa.z, sa.z, ha.z), 0.f) +
                           w2 * fmaxf(fmaf(fb.z, sb.z, hb.z), 0.f));
                o.w = f2bf(w1 * fmaxf(fmaf(fa.w, sa.w, ha.w), 0.f) +
                           w2 * fmaxf(fmaf(fb.w, sb.w, hb.w), 0.f));
                *(ushort4*)&Xs[r * 128 + (c ^ swz)] = o;
            }
        } else {
            ushort4 z = {0, 0, 0, 0};
            *(ushort4*)&Xs[r * 128 + (col0 ^ swz)] = z;
            *(ushort4*)&Xs[r * 128 + ((col0 + 4) ^ swz)] = z;
        }
    }
    __syncthreads();
    f32x4 acc[8];
#pragma unroll
    for (int i = 0; i < 8; ++i) acc[i] = (f32x4){0.f, 0.f, 0.f, 0.f};
    int arow = wave * 16 + m;
#pragma unroll
    for (int kc = 0; kc < 4; ++kc) {
        int ac = (kc * 32 + quad * 8) ^ ((arow & 7) << 3);
        bf16x8 a = *(const bf16x8*)&Xs[arow * 128 + ac];
#pragma unroll
        for (int ct = 0; ct < 8; ++ct) {
            const unsigned short* bp = Wt + ((size_t)(kc * 128 + ct * 16 + m) * 32) + quad * 8;
            bf16x8 b = *(const bf16x8*)bp;
            acc[ct] = __builtin_amdgcn_mfma_f32_16x16x32_bf16(a, b, acc[ct], 0, 0, 0);
        }
    }
#pragma unroll
    for (int ct = 0; ct < 8; ++ct) {
#pragma unroll
        for (int i = 0; i < 4; ++i) {
            int gr = row0 + wave * 16 + quad * 4 + i;
            if (gr < nrows) Y[(size_t)gr * 128 + ct * 16 + m] = f2bf(acc[ct][i]);
        }
    }
}

// ---------------- VALU fused GEMM (final 128->40) ----------------
template <int CG, int RPT>
__global__ __launch_bounds__(256) void gemm_fused_kernel(
    const unsigned short* __restrict__ Abf, const unsigned short* __restrict__ Bbf,
    const float* __restrict__ ss, const float* __restrict__ wout, const float* __restrict__ W,
    unsigned short* __restrict__ Y, int nrows, int fout, int ostride) {
    __shared__ float Ws[32][CG * 4];
    __shared__ float Xs[64][33];
    int tid = threadIdx.x;
    int row0 = blockIdx.x * 64;
    int cg = tid % CG;
    int rg = tid / CG;
    float w1 = wout[0], w2 = wout[1];
    float4 acc[RPT];
#pragma unroll
    for (int i = 0; i < RPT; ++i) acc[i] = make_float4(0.f, 0.f, 0.f, 0.f);
    for (int kc = 0; kc < 4; ++kc) {
        for (int i = tid; i < 32 * CG; i += 256) {
            int r = i / CG, c = i % CG;
            float4 w;
            if ((c * 4 + 3) < fout) {
                w = *(const float4*)(W + (size_t)(kc * 32 + r) * fout + c * 4);
            } else {
                float t0 = (c * 4 + 0) < fout ? W[(size_t)(kc * 32 + r) * fout + c * 4 + 0] : 0.f;
                float t1 = (c * 4 + 1) < fout ? W[(size_t)(kc * 32 + r) * fout + c * 4 + 1] : 0.f;
                float t2 = (c * 4 + 2) < fout ? W[(size_t)(kc * 32 + r) * fout + c * 4 + 2] : 0.f;
                float t3 = (c * 4 + 3) < fout ? W[(size_t)(kc * 32 + r) * fout + c * 4 + 3] : 0.f;
                w = make_float4(t0, t1, t2, t3);
            }
            *(float4*)&Ws[r][c * 4] = w;
        }
        for (int i = tid; i < 64 * 8; i += 256) {
            int r = i / 8, c = i % 8;
            int gr = row0 + r;
            int col0 = kc * 32 + c * 4;
            float4 v = make_float4(0.f, 0.f, 0.f, 0.f);
            if (gr < nrows) {
                float4 a = bf4tof4(*(const ushort4*)(Abf + (size_t)gr * DFEAT + col0));
                float4 b = bf4tof4(*(const ushort4*)(Bbf + (size_t)gr * DFEAT + col0));
                float4 scA = *(const float4*)(ss + col0);
                float4 shA = *(const float4*)(ss + DFEAT + col0);
                float4 scB = *(const float4*)(ss + 2 * DFEAT + col0);
                float4 shB = *(const float4*)(ss + 3 * DFEAT + col0);
                v.x = w1 * fmaxf(fmaf(a.x, scA.x, shA.x), 0.f) +
                      w2 * fmaxf(fmaf(b.x, scB.x, shB.x), 0.f);
                v.y = w1 * fmaxf(fmaf(a.y, scA.y, shA.y), 0.f) +
                      w2 * fmaxf(fmaf(b.y, scB.y, shB.y), 0.f);
                v.z = w1 * fmaxf(fmaf(a.z, scA.z, shA.z), 0.f) +
                      w2 * fmaxf(fmaf(b.z, scB.z, shB.z), 0.f);
                v.w = w1 * fmaxf(fmaf(a.w, scA.w, shA.w), 0.f) +
                      w2 * fmaxf(fmaf(b.w, scB.w, shB.w), 0.f);
            }
            Xs[r][c * 4 + 0] = v.x;
            Xs[r][c * 4 + 1] = v.y;
            Xs[r][c * 4 + 2] = v.z;
            Xs[r][c * 4 + 3] = v.w;
        }
        __syncthreads();
#pragma unroll
        for (int k = 0; k < 32; ++k) {
            float4 w = *(float4*)&Ws[k][cg * 4];
#pragma unroll
            for (int i = 0; i < RPT; ++i) {
                float a = Xs[rg * RPT + i][k];
                acc[i].x = fmaf(a, w.x, acc[i].x);
                acc[i].y = fmaf(a, w.y, acc[i].y);
                acc[i].z = fmaf(a, w.z, acc[i].z);
                acc[i].w = fmaf(a, w.w, acc[i].w);
            }
        }
        __syncthreads();
    }
    if (cg * 4 < fout) {
#pragma unroll
        for (int i = 0; i < RPT; ++i) {
            int r = row0 + rg * RPT + i;
            if (r < nrows) {
                ushort4 o;
                o.x = f2bf(acc[i].x); o.y = f2bf(acc[i].y);
                o.z = f2bf(acc[i].z); o.w = f2bf(acc[i].w);
                *(ushort4*)(Y + (size_t)r * ostride + cg * 4) = o;
            }
        }
    }
}

// ---------------- BN statistics: vectorized int4 loads + shfl/LDS reduce ----------------
__global__ __launch_bounds__(256) void stats2_kernel(const unsigned short* __restrict__ A,
                                                     const unsigned short* __restrict__ B,
                                                     float* __restrict__ stats, int nrows) {
    const unsigned short* src = (blockIdx.y == 0) ? A : B;
    float* st = stats + (size_t)blockIdx.y * 256;
    int t = threadIdx.x;
    int li = t & 15;      // col group (8 cols)
    int rg = t >> 4;      // row offset 0..15
    int base = blockIdx.x * 128;
    float s[8] = {0.f, 0.f, 0.f, 0.f, 0.f, 0.f, 0.f, 0.f};
    float s2[8] = {0.f, 0.f, 0.f, 0.f, 0.f, 0.f, 0.f, 0.f};
#pragma unroll
    for (int i = 0; i < 8; ++i) {
        int r = base + i * 16 + rg;
        if (r < nrows) {
            int4 v = *(const int4*)(src + (size_t)r * DFEAT + li * 8);
            int vs[4] = {v.x, v.y, v.z, v.w};
#pragma unroll
            for (int q = 0; q < 4; ++q) {
                float lo = __uint_as_float((unsigned)vs[q] << 16);
                float hi = __uint_as_float((unsigned)vs[q] & 0xffff0000u);
                s[q * 2] += lo;
                s2[q * 2] = fmaf(lo, lo, s2[q * 2]);
                s[q * 2 + 1] += hi;
                s2[q * 2 + 1] = fmaf(hi, hi, s2[q * 2 + 1]);
            }
        }
    }
    // reduce across the 4 rg-values within each wave (lanes differing by 16/32)
#pragma unroll
    for (int j = 0; j < 8; ++j) {
        s[j] += __shfl_xor(s[j], 16);
        s[j] += __shfl_xor(s[j], 32);
        s2[j] += __shfl_xor(s2[j], 16);
        s2[j] += __shfl_xor(s2[j], 32);
    }
    __shared__ float red1[4][16][8];
    __shared__ float red2[4][16][8];
    int wave = t >> 6, lane = t & 63;
    if (lane < 16) {
#pragma unroll
        for (int j = 0; j < 8; ++j) {
            red1[wave][lane][j] = s[j];
            red2[wave][lane][j] = s2[j];
        }
    }
    __syncthreads();
    if (t < 128) {  // t = column index
        int cg = t >> 3, el = t & 7;
        float a = red1[0][cg][el] + red1[1][cg][el] + red1[2][cg][el] + red1[3][cg][el];
        float b = red2[0][cg][el] + red2[1][cg][el] + red2[2][cg][el] + red2[3][cg][el];
        atomicAdd(&st[t], a);
        atomicAdd(&st[DFEAT + t], b);
    }
}

// ---------------- BN scale/shift + gates; zeros stats for next layer ----------------
__global__ __launch_bounds__(128) void gate_prep_kernel(
    float* __restrict__ statsA, float* __restrict__ statsB,
    const unsigned short* __restrict__ preA, const unsigned short* __restrict__ preB,
    const float* __restrict__ gamma, const float* __restrict__ beta,
    const float* __restrict__ gwA, const float* __restrict__ gbA,
    const float* __restrict__ gwB, const float* __restrict__ gbB,
    float* __restrict__ ss, float* __restrict__ wout, int nrows) {
    __shared__ float red[128];
    __shared__ float dotA_s;
    int t = threadIdx.x;
    float invN = 1.f / (float)nrows;
    float meanA = statsA[t] * invN;
    float varA = statsA[DFEAT + t] * invN - meanA * meanA;
    float scA = gamma[t] * rsqrtf(varA + 1e-5f);
    float shA = beta[t] - meanA * scA;
    ss[t] = scA;
    ss[DFEAT + t] = shA;
    float meanB = statsB[t] * invN;
    float varB = statsB[DFEAT + t] * invN - meanB * meanB;
    float scB = gamma[t] * rsqrtf(varB + 1e-5f);
    float shB = beta[t] - meanB * scB;
    ss[2 * DFEAT + t] = scB;
    ss[3 * DFEAT + t] = shB;
    statsA[t] = 0.f;
    statsA[DFEAT + t] = 0.f;
    statsB[t] = 0.f;
    statsB[DFEAT + t] = 0.f;
    float av = fmaxf(fmaf(bf2f(preA[(size_t)(nrows - 1) * DFEAT + t]), scA, shA), 0.f);
    red[t] = av * gwA[t];
    __syncthreads();
    for (int s = 64; s > 0; s >>= 1) {
        if (t < s) red[t] += red[t + s];
        __syncthreads();
    }
    if (t == 0) dotA_s = red[0];
    __syncthreads();
    float bv = fmaxf(fmaf(bf2f(preB[(size_t)(nrows - 1) * DFEAT + t]), scB, shB), 0.f);
    red[t] = bv * gwB[t];
    __syncthreads();
    for (int s = 64; s > 0; s >>= 1) {
        if (t < s) red[t] += red[t + s];
        __syncthreads();
    }
    if (t == 0) {
        float s1 = 1.f / (1.f + expf(-(dotA_s + gbA[0])));
        float s2 = 1.f / (1.f + expf(-(red[0] + gbB[0])));
        float tt = s1 + s2;
        wout[0] = s1 / tt;
        wout[1] = s2 / tt;
    }
}

__global__ __launch_bounds__(64) void gate_final_kernel(
    const float* __restrict__ p1, const float* __restrict__ p2,
    const float* __restrict__ w1v, const float* __restrict__ b1,
    const float* __restrict__ w2v, const float* __restrict__ b2,
    float* __restrict__ wout, int nrows, int nclass) {
    __shared__ float red[64];
    __shared__ float dot1_s;
    int t = threadIdx.x;
    float v = (t < nclass) ? p1[(size_t)(nrows - 1) * nclass + t] * w1v[t] : 0.f;
    red[t] = v;
    __syncthreads();
    for (int s = 32; s > 0; s >>= 1) {
        if (t < s) red[t] += red[t + s];
        __syncthreads();
    }
    if (t == 0) dot1_s = red[0];
    __syncthreads();
    v = (t < nclass) ? p2[(size_t)(nrows - 1) * nclass + t] * w2v[t] : 0.f;
    red[t] = v;
    __syncthreads();
    for (int s = 32; s > 0; s >>= 1) {
        if (t < s) red[t] += red[t + s];
        __syncthreads();
    }
    if (t == 0) {
        float s1 = 1.f / (1.f + expf(-(dot1_s + b1[0])));
        float s2 = 1.f / (1.f + expf(-(red[0] + b2[0])));
        float tt = s1 + s2;
        wout[0] = s1 / tt;
        wout[1] = s2 / tt;
    }
}

__global__ __launch_bounds__(256) void mix_kernel(const float* __restrict__ p1,
                                                  const float* __restrict__ p2,
                                                  const float* __restrict__ wout,
                                                  float* __restrict__ o, int n4) {
    int idx = blockIdx.x * blockDim.x + threadIdx.x;
    if (idx >= n4) return;
    float w1 = wout[0], w2 = wout[1];
    float4 a = *(const float4*)(p1 + (size_t)idx * 4);
    float4 b = *(const float4*)(p2 + (size_t)idx * 4);
    float4 r = make_float4(w1 * a.x + w2 * b.x, w1 * a.y + w2 * b.y, w1 * a.z + w2 * b.z,
                           w1 * a.w + w2 * b.w);
    *(float4*)(o + (size_t)idx * 4) = r;
}

extern "C" void kernel_launch(void* const* d_in, const int* in_sizes, int n_in, void* d_out,
                              int out_size, void* d_ws, size_t ws_size, hipStream_t stream) {
    (void)n_in; (void)out_size; (void)ws_size;
    const int N = in_sizes[0] / DFEAT;        // 50000
    const int E = in_sizes[4] / 2;            // 800000
    const int NC = in_sizes[15];              // 40

    const float* x1a = (const float*)d_in[0];
    const float* x1b = (const float*)d_in[1];
    const float* x2a = (const float*)d_in[2];
    const float* x2b = (const float*)d_in[3];
    const int* ei1 = (const int*)d_in[4];
    const int* ei2 = (const int*)d_in[5];
    const float* Wi = (const float*)d_in[6];
    const float* bi = (const float*)d_in[7];
    const float* gi = (const float*)d_in[8];
    const float* bei = (const float*)d_in[9];
    const float* Wm = (const float*)d_in[10];
    const float* bm = (const float*)d_in[11];
    const float* gm = (const float*)d_in[12];
    const float* bem = (const float*)d_in[13];
    const float* Wf = (const float*)d_in[14];
    const float* bf = (const float*)d_in[15];
    const float* fc1w1_W = (const float*)d_in[16];
    const float* fc1w1_b = (const float*)d_in[17];
    const float* fc1w2_W = (const float*)d_in[18];
    const float* fc1w2_b = (const float*)d_in[19];
    const float* aws_w1_W = (const float*)d_in[20];
    const float* aws_w1_b = (const float*)d_in[21];
    const float* aws_w2_W = (const float*)d_in[22];
    const float* aws_w2_b = (const float*)d_in[23];
    const float* fcw1_W = (const float*)d_in[24];
    const float* fcw1_b = (const float*)d_in[25];
    const float* fcw2_W = (const float*)d_in[26];
    const float* fcw2_b = (const float*)d_in[27];

    char* ws = (char*)d_ws;
    size_t off = 0;
    auto alloc = [&](size_t bytes) -> char* {
        char* p = ws + off;
        off += (bytes + 255) & ~(size_t)255;
        return p;
    };
    unsigned short* A = (unsigned short*)alloc((size_t)N * DFEAT * 2);
    unsigned short* B = (unsigned short*)alloc((size_t)N * DFEAT * 2);
    unsigned short* H1 = (unsigned short*)alloc((size_t)N * DFEAT * 2);
    unsigned short* H2 = (unsigned short*)alloc((size_t)N * DFEAT * 2);
    int* rp1 = (int*)alloc((size_t)(N + 1) * 4);
    int* rp2 = (int*)alloc((size_t)(N + 1) * 4);
    int* cnt1 = (int*)alloc((size_t)N * 4);
    int* cnt2 = (int*)alloc((size_t)N * 4);
    float* dv1 = (float*)alloc((size_t)N * 4);
    float* dv2 = (float*)alloc((size_t)N * 4);
    int* cs1 = (int*)alloc((size_t)E * 4);
    int* cs2 = (int*)alloc((size_t)E * 4);
    int* stg = (int*)alloc((size_t)2 * NRMAX * SCAP * 4);             // 10.2 MB
    int* baseB = (int*)alloc(((size_t)2 * NRMAX * SUBS << RSH) * 4);  // 16.8 MB
    int* gcount = (int*)alloc(32 * 4);
    unsigned short* Wt = (unsigned short*)alloc((size_t)2 * 16384 * 2);
    unsigned short* Wt1 = (unsigned short*)alloc((size_t)32768 * 2);  // 64 KB
    float* stats = (float*)alloc(2048);
    float* statsA = stats;
    float* statsB = stats + 256;
    float* ssbuf = (float*)alloc(2048);
    float* wout = (float*)alloc(256);
    int nb = (N + 255) / 256;                 // 196 (scanB/writerp blocking, <=256)
    int* bsums = (int*)alloc((size_t)2 * nb * 4);

    const int* src1 = ei1;
    const int* dst1 = ei1 + E;
    const int* src2 = ei2;
    const int* dst2 = ei2 + E;

    int nr = (N + RSZ - 1) >> RSH;            // 7
    int gemmbl = (N + 63) / 64;
    dim3 pagrid((E + EPA - 1) / EPA, 2);      // 391 x 2
    dim3 rsgrid(nr * SUBS, 2);                // 112 x 2
    dim3 nodegrid(nb, 2);
    dim3 agggrid((N + 3) / 4, 2);
    dim3 statgrid((N + 127) / 128, 2);
    dim3 l1grid(gemmbl, 4);

    // ---- prep + CSR build (two-level counting sort, LDS atomics only) ----
    prep_kernel<<<257, 256, 0, stream>>>(Wm, Wi, Wt, Wt1, gcount);
    partA_kernel<<<pagrid, 256, 0, stream>>>(src1, dst1, src2, dst2, stg, gcount, E, nr);
    histB_kernel<<<rsgrid, 256, 0, stream>>>(stg, gcount, baseB, nr);
    scanB_kernel<<<nodegrid, 256, 0, stream>>>(baseB, cnt1, cnt2, bsums, N, nb);
    scansums_kernel<<<1, 256, 0, stream>>>(bsums, nb, rp1, rp2, N, E, stats);
    writerp_kernel<<<nodegrid, 256, 0, stream>>>(cnt1, cnt2, bsums, rp1, rp2, dv1, dv2, N, nb);
    fillC_kernel<<<rsgrid, 256, 0, stream>>>(stg, gcount, baseB, rp1, rp2, dv1, dv2,
                                             cs1, cs2, N, nr);

    // ---- Layer 1 ----
    gemm_l1_kernel<<<l1grid, 256, 0, stream>>>(x1a, x1b, x2a, x2b, Wt1, H1, H2, N);
    dualagg_kernel<128, unsigned short><<<agggrid, 256, 0, stream>>>(
        H1, H2, rp1, cs1, dv1, rp2, cs2, dv2, bi, A, B, N);
    stats2_kernel<<<statgrid, 256, 0, stream>>>(A, B, stats, N);
    gate_prep_kernel<<<1, 128, 0, stream>>>(statsA, statsB, A, B, gi, bei, fc1w1_W, fc1w1_b,
                                            fc1w2_W, fc1w2_b, ssbuf, wout, N);

    // ---- Middle layer 0 ----
    gemm_mfma_kernel<<<gemmbl, 256, 0, stream>>>(A, B, ssbuf, wout, Wt, H1, N);
    dualagg_kernel<128, unsigned short><<<agggrid, 256, 0, stream>>>(
        H1, H1, rp1, cs1, dv1, rp2, cs2, dv2, bm, A, B, N);
    stats2_kernel<<<statgrid, 256, 0, stream>>>(A, B, stats, N);
    gate_prep_kernel<<<1, 128, 0, stream>>>(statsA, statsB, A, B, gm, bem, aws_w1_W, aws_w1_b,
                                            aws_w2_W, aws_w2_b, ssbuf, wout, N);

    // ---- Middle layer 1 ----
    gemm_mfma_kernel<<<gemmbl, 256, 0, stream>>>(A, B, ssbuf, wout, Wt + 16384, H1, N);
    dualagg_kernel<128, unsigned short><<<agggrid, 256, 0, stream>>>(
        H1, H1, rp1, cs1, dv1, rp2, cs2, dv2, bm + 128, A, B, N);
    stats2_kernel<<<statgrid, 256, 0, stream>>>(A, B, stats, N);
    gate_prep_kernel<<<1, 128, 0, stream>>>(statsA, statsB, A, B, gm + 128, bem + 128,
                                            aws_w1_W + 128, aws_w1_b + 1, aws_w2_W + 128,
                                            aws_w2_b + 1, ssbuf, wout, N);

    // ---- Final layer ----
    float* out0 = (float*)d_out;
    float* p1 = out0 + (size_t)N * NC;
    float* p2 = out0 + (size_t)2 * N * NC;
    gemm_fused_kernel<16, 4><<<gemmbl, 256, 0, stream>>>(A, B, ssbuf, wout, Wf, H2, N, NC, NC);
    dualagg_kernel<40, float><<<agggrid, 256, 0, stream>>>(H2, H2, rp1, cs1, dv1, rp2, cs2, dv2,
                                                           bf, p1, p2, N);
    gate_final_kernel<<<1, 64, 0, stream>>>(p1, p2, fcw1_W, fcw1_b, fcw2_W, fcw2_b, wout, N, NC);
    mix_kernel<<<(N * NC / 4 + 255) / 256, 256, 0, stream>>>(p1, p2, wout, out0, N * NC / 4);
}